// Round 1
// baseline (540.545 us; speedup 1.0000x reference)
//
#include <hip/hip_runtime.h>

#define NDIM 2048
#define NB 512      // B*C packed columns
#define BDIM 8
#define CDIM 64

// ---------------- pack X (B,N,C) -> Xt (N, B*C) ----------------
__global__ __launch_bounds__(256) void pack_x(const float* __restrict__ X,
                                              float* __restrict__ Xt) {
    int idx = blockIdx.x * 256 + threadIdx.x;      // b*N*C + n*C + c
    int c = idx & 63;
    int n = (idx >> 6) & 2047;
    int b = idx >> 17;
    Xt[n * NB + b * 64 + c] = X[idx];
}

// ---------------- f32 GEMM: 64x64 tile, 4x4 microtile ----------------
// MODE 0: dual-A stacked  (bx<32: C0 = A0@B ; bx>=32: C1 = A1@B)
// MODE 1: Chebyshev step  C0 = 2*A0@B - Cin
template <int MODE>
__global__ __launch_bounds__(256) void gemm64(const float* __restrict__ A0,
                                              const float* __restrict__ A1,
                                              const float* __restrict__ Bm,
                                              const float* __restrict__ Cin,
                                              float* __restrict__ C0,
                                              float* __restrict__ C1) {
    __shared__ float As[16][68];   // transposed A tile, padded
    __shared__ float Bs[16][64];
    const int t = threadIdx.x;
    const int tx = t & 15, ty = t >> 4;

    const float* A;
    float* Cout;
    int orow;
    if (MODE == 0) {
        if (blockIdx.x < 32) { A = A0; Cout = C0; orow = blockIdx.x * 64; }
        else                 { A = A1; Cout = C1; orow = (blockIdx.x - 32) * 64; }
    } else {
        A = A0; Cout = C0; orow = blockIdx.x * 64;
    }
    const int ncol = blockIdx.y * 64;

    const int am = t >> 2;           // 0..63 (A tile row)
    const int ak = (t & 3) << 2;     // 0,4,8,12 (A tile col base)
    const int bk = t >> 4;           // 0..15 (B tile row)
    const int bn = (t & 15) << 2;    // 0..60 (B tile col base)
    const float* Ap = A + (orow + am) * NDIM + ak;
    const float* Bp = Bm + bk * NB + ncol + bn;

    float acc[4][4] = {{0.f, 0.f, 0.f, 0.f}, {0.f, 0.f, 0.f, 0.f},
                       {0.f, 0.f, 0.f, 0.f}, {0.f, 0.f, 0.f, 0.f}};

    for (int k0 = 0; k0 < NDIM; k0 += 16) {
        float4 av = *(const float4*)(Ap + k0);
        float4 bv = *(const float4*)(Bp + k0 * NB);
        if (k0) __syncthreads();
        As[ak + 0][am] = av.x;
        As[ak + 1][am] = av.y;
        As[ak + 2][am] = av.z;
        As[ak + 3][am] = av.w;
        *(float4*)&Bs[bk][bn] = bv;
        __syncthreads();
#pragma unroll
        for (int kk = 0; kk < 16; ++kk) {
            float4 a = *(const float4*)&As[kk][ty * 4];
            float4 b = *(const float4*)&Bs[kk][tx * 4];
            float ar[4] = {a.x, a.y, a.z, a.w};
            float br[4] = {b.x, b.y, b.z, b.w};
#pragma unroll
            for (int i = 0; i < 4; ++i)
#pragma unroll
                for (int j = 0; j < 4; ++j)
                    acc[i][j] = fmaf(ar[i], br[j], acc[i][j]);
        }
    }

#pragma unroll
    for (int i = 0; i < 4; ++i) {
        const int row = orow + ty * 4 + i;
        const int col = ncol + tx * 4;
        float4 v = make_float4(acc[i][0], acc[i][1], acc[i][2], acc[i][3]);
        if (MODE == 1) {
            float4 ci = *(const float4*)&Cin[row * NB + col];
            v.x = 2.f * v.x - ci.x;
            v.y = 2.f * v.y - ci.y;
            v.z = 2.f * v.z - ci.z;
            v.w = 2.f * v.w - ci.w;
        }
        *(float4*)&Cout[row * NB + col] = v;
    }
}

// ---------------- G[b] = WaX[b]^T @ X[b], partial over N chunks ----------------
__global__ __launch_bounds__(256) void gram_partial(const float* __restrict__ WaXt,
                                                    const float* __restrict__ Xt,
                                                    float* __restrict__ Gpart) {
    const int b = blockIdx.x;
    const int chunk = blockIdx.y;   // 8 chunks of 256 rows
    __shared__ float Ls[8][64];
    __shared__ float Rs[8][64];
    const int t = threadIdx.x;
    const int tx = t & 15, ty = t >> 4;
    const int lr = t >> 5;          // 0..7
    const int lc = (t & 31) * 2;    // 0..62
    const int base = b * 64;
    float acc[4][4] = {{0.f, 0.f, 0.f, 0.f}, {0.f, 0.f, 0.f, 0.f},
                       {0.f, 0.f, 0.f, 0.f}, {0.f, 0.f, 0.f, 0.f}};
    const int nstart = chunk * 256;
    for (int n0 = nstart; n0 < nstart + 256; n0 += 8) {
        float2 wv = *(const float2*)&WaXt[(n0 + lr) * NB + base + lc];
        float2 xv = *(const float2*)&Xt[(n0 + lr) * NB + base + lc];
        if (n0 != nstart) __syncthreads();
        Ls[lr][lc] = wv.x; Ls[lr][lc + 1] = wv.y;
        Rs[lr][lc] = xv.x; Rs[lr][lc + 1] = xv.y;
        __syncthreads();
#pragma unroll
        for (int r = 0; r < 8; ++r) {
            float4 a = *(const float4*)&Ls[r][ty * 4];
            float4 bb = *(const float4*)&Rs[r][tx * 4];
            float ar[4] = {a.x, a.y, a.z, a.w};
            float br[4] = {bb.x, bb.y, bb.z, bb.w};
#pragma unroll
            for (int i = 0; i < 4; ++i)
#pragma unroll
                for (int j = 0; j < 4; ++j)
                    acc[i][j] = fmaf(ar[i], br[j], acc[i][j]);
        }
    }
    float* gp = Gpart + (chunk * BDIM + b) * 4096;
#pragma unroll
    for (int i = 0; i < 4; ++i)
        *(float4*)&gp[(ty * 4 + i) * 64 + tx * 4] =
            make_float4(acc[i][0], acc[i][1], acc[i][2], acc[i][3]);
}

__global__ __launch_bounds__(256) void reduce_g(const float* __restrict__ Gpart,
                                                float* __restrict__ G) {
    int idx = blockIdx.x * 256 + threadIdx.x;   // B*4096 total
    float s = 0.f;
#pragma unroll
    for (int c = 0; c < 8; ++c) s += Gpart[c * (BDIM * 4096) + idx];
    G[idx] = s;
}

// ---------------- per-batch 64x64 Chebyshev + D = sum_k C_k @ Thd[k] ----------------
__global__ __launch_bounds__(256) void cheb_d(const float* __restrict__ G,
                                              const float* __restrict__ Thd,
                                              float* __restrict__ D) {
    const int b = blockIdx.x;
    __shared__ float Gs[64][68];
    __shared__ float C2s[64][68];
    __shared__ float C3s[64][68];
    const int t = threadIdx.x;
    const int tx = t & 15, ty = t >> 4;
    for (int i = t; i < 4096; i += 256) Gs[i >> 6][i & 63] = G[b * 4096 + i];
    __syncthreads();
    const int r0 = ty * 4, c0 = tx * 4;

    // P = G@G ; C2 = 2P - I
    float p[4][4] = {{0.f, 0.f, 0.f, 0.f}, {0.f, 0.f, 0.f, 0.f},
                     {0.f, 0.f, 0.f, 0.f}, {0.f, 0.f, 0.f, 0.f}};
    for (int k = 0; k < 64; ++k) {
        float ar[4] = {Gs[r0][k], Gs[r0 + 1][k], Gs[r0 + 2][k], Gs[r0 + 3][k]};
        float4 bv = *(const float4*)&Gs[k][c0];
        float br[4] = {bv.x, bv.y, bv.z, bv.w};
#pragma unroll
        for (int i = 0; i < 4; ++i)
#pragma unroll
            for (int j = 0; j < 4; ++j) p[i][j] = fmaf(ar[i], br[j], p[i][j]);
    }
#pragma unroll
    for (int i = 0; i < 4; ++i)
#pragma unroll
        for (int j = 0; j < 4; ++j)
            C2s[r0 + i][c0 + j] = 2.f * p[i][j] - ((r0 + i) == (c0 + j) ? 1.f : 0.f);
    __syncthreads();

    // Q = G@C2 ; C3 = 2Q - G
    float q[4][4] = {{0.f, 0.f, 0.f, 0.f}, {0.f, 0.f, 0.f, 0.f},
                     {0.f, 0.f, 0.f, 0.f}, {0.f, 0.f, 0.f, 0.f}};
    for (int k = 0; k < 64; ++k) {
        float ar[4] = {Gs[r0][k], Gs[r0 + 1][k], Gs[r0 + 2][k], Gs[r0 + 3][k]};
        float4 bv = *(const float4*)&C2s[k][c0];
        float br[4] = {bv.x, bv.y, bv.z, bv.w};
#pragma unroll
        for (int i = 0; i < 4; ++i)
#pragma unroll
            for (int j = 0; j < 4; ++j) q[i][j] = fmaf(ar[i], br[j], q[i][j]);
    }
#pragma unroll
    for (int i = 0; i < 4; ++i)
#pragma unroll
        for (int j = 0; j < 4; ++j)
            C3s[r0 + i][c0 + j] = 2.f * q[i][j] - Gs[r0 + i][c0 + j];
    __syncthreads();

    // D = Thd0 + G@Thd1 + C2@Thd2 + C3@Thd3
    float d[4][4];
#pragma unroll
    for (int i = 0; i < 4; ++i) {
        float4 t0 = *(const float4*)&Thd[(r0 + i) * 64 + c0];
        d[i][0] = t0.x; d[i][1] = t0.y; d[i][2] = t0.z; d[i][3] = t0.w;
    }
    for (int k = 0; k < 64; ++k) {
        float4 t1 = *(const float4*)&Thd[4096 + k * 64 + c0];
        float4 t2 = *(const float4*)&Thd[8192 + k * 64 + c0];
        float4 t3 = *(const float4*)&Thd[12288 + k * 64 + c0];
        float a1[4] = {Gs[r0][k], Gs[r0 + 1][k], Gs[r0 + 2][k], Gs[r0 + 3][k]};
        float a2[4] = {C2s[r0][k], C2s[r0 + 1][k], C2s[r0 + 2][k], C2s[r0 + 3][k]};
        float a3[4] = {C3s[r0][k], C3s[r0 + 1][k], C3s[r0 + 2][k], C3s[r0 + 3][k]};
        float b1[4] = {t1.x, t1.y, t1.z, t1.w};
        float b2[4] = {t2.x, t2.y, t2.z, t2.w};
        float b3[4] = {t3.x, t3.y, t3.z, t3.w};
#pragma unroll
        for (int i = 0; i < 4; ++i)
#pragma unroll
            for (int j = 0; j < 4; ++j) {
                d[i][j] = fmaf(a1[i], b1[j], d[i][j]);
                d[i][j] = fmaf(a2[i], b2[j], d[i][j]);
                d[i][j] = fmaf(a3[i], b3[j], d[i][j]);
            }
    }
#pragma unroll
    for (int i = 0; i < 4; ++i)
        *(float4*)&D[b * 4096 + (r0 + i) * 64 + c0] =
            make_float4(d[i][0], d[i][1], d[i][2], d[i][3]);
}

// ---------------- epilogue 1: out = relu(static) ----------------
__global__ __launch_bounds__(256) void ep_static(const float* __restrict__ Xt,
                                                 const float* __restrict__ Y1,
                                                 const float* __restrict__ Y2,
                                                 const float* __restrict__ Y3,
                                                 const float* __restrict__ Ths,
                                                 float* __restrict__ out) {
    const int b = blockIdx.y;
    const int r0 = blockIdx.x * 64;
    __shared__ float Ts[4][64][64];   // 64 KiB exactly
    const int t = threadIdx.x;
    for (int i = t; i < 4096; i += 256) {
        int r = i >> 6, c = i & 63;
        Ts[0][r][c] = Ths[i];
        Ts[1][r][c] = Ths[4096 + i];
        Ts[2][r][c] = Ths[8192 + i];
        Ts[3][r][c] = Ths[12288 + i];
    }
    __syncthreads();
    const int c = t & 63, w = t >> 6;
    const int base = b * 64;
    for (int r = w; r < 64; r += 4) {
        const int n = r0 + r;
        float xc = Xt[n * NB + base + c];
        float y1 = Y1[n * NB + base + c];
        float y2 = Y2[n * NB + base + c];
        float y3 = Y3[n * NB + base + c];
        float s = 0.f;
#pragma unroll
        for (int i = 0; i < 64; ++i) {
            s = fmaf(__shfl(xc, i), Ts[0][i][c], s);
            s = fmaf(__shfl(y1, i), Ts[1][i][c], s);
            s = fmaf(__shfl(y2, i), Ts[2][i][c], s);
            s = fmaf(__shfl(y3, i), Ts[3][i][c], s);
        }
        out[b * (NDIM * 64) + n * 64 + c] = fmaxf(s, 0.f);
    }
}

// ---------------- epilogue 2: out += relu(X @ D[b]) ----------------
__global__ __launch_bounds__(256) void ep_dyn(const float* __restrict__ Xt,
                                              const float* __restrict__ D,
                                              float* __restrict__ out) {
    const int b = blockIdx.y;
    const int r0 = blockIdx.x * 64;
    __shared__ float Ds[64][64];
    const int t = threadIdx.x;
    for (int i = t; i < 4096; i += 256) Ds[i >> 6][i & 63] = D[b * 4096 + i];
    __syncthreads();
    const int c = t & 63, w = t >> 6;
    for (int r = w; r < 64; r += 4) {
        const int n = r0 + r;
        float xc = Xt[n * NB + b * 64 + c];
        float s = 0.f;
#pragma unroll
        for (int i = 0; i < 64; ++i) s = fmaf(__shfl(xc, i), Ds[i][c], s);
        const int o = b * (NDIM * 64) + n * 64 + c;
        out[o] = out[o] + fmaxf(s, 0.f);
    }
}

extern "C" void kernel_launch(void* const* d_in, const int* in_sizes, int n_in,
                              void* d_out, int out_size, void* d_ws, size_t ws_size,
                              hipStream_t stream) {
    const float* X   = (const float*)d_in[0];
    const float* Ws  = (const float*)d_in[1];
    const float* Wa  = (const float*)d_in[2];
    const float* Ths = (const float*)d_in[3];
    const float* Thd = (const float*)d_in[4];
    float* out = (float*)d_out;

    // workspace layout (floats): 5x 1M big buffers + G partials + G + D
    const size_t need = (5u * (1u << 20) + 8u * BDIM * 4096u + 2u * BDIM * 4096u) * 4u;
    if (ws_size < need) return;  // visible failure, no corruption

    float* Xt    = (float*)d_ws;
    float* Y1    = Xt + (1 << 20);
    float* Y2    = Y1 + (1 << 20);
    float* Y3    = Y2 + (1 << 20);
    float* WaXt  = Y3 + (1 << 20);
    float* Gpart = WaXt + (1 << 20);
    float* G     = Gpart + 8 * BDIM * 4096;
    float* D     = G + BDIM * 4096;

    pack_x<<<4096, 256, 0, stream>>>(X, Xt);
    // Y1 = Ws@Xt ; WaXt = W_alpha@Xt   (stacked 4096x512x2048 GEMM)
    gemm64<0><<<dim3(64, 8), 256, 0, stream>>>(Ws, Wa, Xt, nullptr, Y1, WaXt);
    // Y2 = 2*Ws@Y1 - Xt ; Y3 = 2*Ws@Y2 - Y1
    gemm64<1><<<dim3(32, 8), 256, 0, stream>>>(Ws, nullptr, Y1, Xt, Y2, nullptr);
    gemm64<1><<<dim3(32, 8), 256, 0, stream>>>(Ws, nullptr, Y2, Y1, Y3, nullptr);
    // G[b] = WaX[b]^T @ X[b]
    gram_partial<<<dim3(BDIM, 8), 256, 0, stream>>>(WaXt, Xt, Gpart);
    reduce_g<<<BDIM * 4096 / 256, 256, 0, stream>>>(Gpart, G);
    // D[b] = Thd0 + C1@Thd1 + C2@Thd2 + C3@Thd3
    cheb_d<<<BDIM, 256, 0, stream>>>(G, Thd, D);
    // out = relu(static) ; out += relu(X@D)
    ep_static<<<dim3(32, BDIM), 256, 0, stream>>>(Xt, Y1, Y2, Y3, Ths, out);
    ep_dyn<<<dim3(32, BDIM), 256, 0, stream>>>(Xt, D, out);
}

// Round 2
// 177.889 us; speedup vs baseline: 3.0387x; 3.0387x over previous
//
#include <hip/hip_runtime.h>

typedef __attribute__((ext_vector_type(8))) short bf16x8;
typedef __attribute__((ext_vector_type(4))) float f32x4;

__device__ __forceinline__ ushort f32_to_bf16(float f) {
    union { float f; unsigned u; } v; v.f = f;
    unsigned b = v.u + 0x7FFF + ((v.u >> 16) & 1);
    return (ushort)(b >> 16);
}
__device__ __forceinline__ float bf16_to_f32(ushort h) {
    union { unsigned u; float f; } v; v.u = ((unsigned)h) << 16;
    return v.f;
}
__device__ __forceinline__ void split3(float x, ushort& a, ushort& b, ushort& c) {
    a = f32_to_bf16(x); float r1 = x - bf16_to_f32(a);
    b = f32_to_bf16(r1); float r2 = r1 - bf16_to_f32(b);
    c = f32_to_bf16(r2);
}
__device__ __forceinline__ void split2(float x, ushort& a, ushort& b) {
    a = f32_to_bf16(x); float r1 = x - bf16_to_f32(a);
    b = f32_to_bf16(r1);
}

// Stage a 64-row x 128-byte tile from global (row-major, row_stride elems of bf16)
// into 8KB of LDS, with st-style XOR swizzle applied via the GLOBAL source address
// (linear LDS dest as global_load_lds requires; read side applies the same XOR).
__device__ __forceinline__ void stage64x64(const ushort* gsrc, int row_stride_elems,
                                           char* lds, int t) {
    const char* gb = (const char*)gsrc;
    const int rs = row_stride_elems * 2;
#pragma unroll
    for (int j = 0; j < 2; ++j) {
        int o = (j * 256 + t) * 16;
        int row = o >> 7;
        int col = (o & 127) ^ ((row & 7) << 4);
        __builtin_amdgcn_global_load_lds(
            (const __attribute__((address_space(1))) unsigned int*)(gb + row * rs + col),
            (__attribute__((address_space(3))) unsigned int*)(lds + o), 16, 0, 0);
    }
}

__device__ __forceinline__ bf16x8 fragld(const char* lds, int row, int kbyte) {
    return *(const bf16x8*)(lds + (row << 7) + (kbyte ^ ((row & 7) << 4)));
}

// ---------------- prep: X (B,2048,64) f32 -> XT splits [512][2048], orig splits [2048][512]
__global__ __launch_bounds__(256) void prep_xt(const float* __restrict__ X,
                                               ushort* __restrict__ XT1, ushort* __restrict__ XT2,
                                               ushort* __restrict__ XT3,
                                               ushort* __restrict__ X1o, ushort* __restrict__ X2o) {
    const int b = blockIdx.y, n0 = blockIdx.x * 64;
    __shared__ float tile[64][68];
    const int t = threadIdx.x;
#pragma unroll
    for (int it = 0; it < 4; ++it) {
        int f = it * 256 + t, r = f >> 4, q = (f & 15) * 4;
        float4 v = *(const float4*)&X[((size_t)b * 2048 + n0 + r) * 64 + q];
        tile[r][q + 0] = v.x; tile[r][q + 1] = v.y; tile[r][q + 2] = v.z; tile[r][q + 3] = v.w;
    }
    __syncthreads();
#pragma unroll
    for (int it = 0; it < 4; ++it) {   // T-layout: row = b*64+c, cols n
        int f = it * 256 + t, c = f >> 4, q = (f & 15) * 4;
        float v0 = tile[q + 0][c], v1 = tile[q + 1][c], v2 = tile[q + 2][c], v3 = tile[q + 3][c];
        ushort4 h1, h2, h3;
        split3(v0, h1.x, h2.x, h3.x); split3(v1, h1.y, h2.y, h3.y);
        split3(v2, h1.z, h2.z, h3.z); split3(v3, h1.w, h2.w, h3.w);
        size_t a = (size_t)(b * 64 + c) * 2048 + n0 + q;
        *(ushort4*)&XT1[a] = h1; *(ushort4*)&XT2[a] = h2; *(ushort4*)&XT3[a] = h3;
    }
#pragma unroll
    for (int it = 0; it < 4; ++it) {   // orig layout: row n, cols bc
        int f = it * 256 + t, n = f >> 4, q = (f & 15) * 4;
        float v0 = tile[n][q + 0], v1 = tile[n][q + 1], v2 = tile[n][q + 2], v3 = tile[n][q + 3];
        ushort4 h1, h2;
        split2(v0, h1.x, h2.x); split2(v1, h1.y, h2.y);
        split2(v2, h1.z, h2.z); split2(v3, h1.w, h2.w);
        size_t a = (size_t)(n0 + n) * 512 + b * 64 + q;
        *(ushort4*)&X1o[a] = h1; *(ushort4*)&X2o[a] = h2;
    }
}

__global__ __launch_bounds__(256) void conv_ws(const float* __restrict__ W, ushort* __restrict__ W1) {
    size_t idx = ((size_t)blockIdx.x * 256 + threadIdx.x) * 4;
    float4 v = *(const float4*)&W[idx];
    ushort4 a;
    a.x = f32_to_bf16(v.x); a.y = f32_to_bf16(v.y); a.z = f32_to_bf16(v.z); a.w = f32_to_bf16(v.w);
    *(ushort4*)&W1[idx] = a;
}

__global__ __launch_bounds__(256) void conv_wa(const float* __restrict__ W, ushort* __restrict__ W1,
                                               ushort* __restrict__ W2, ushort* __restrict__ W3) {
    size_t idx = ((size_t)blockIdx.x * 256 + threadIdx.x) * 4;
    float4 v = *(const float4*)&W[idx];
    ushort4 a, b, c;
    split3(v.x, a.x, b.x, c.x); split3(v.y, a.y, b.y, c.y);
    split3(v.z, a.z, b.z, c.z); split3(v.w, a.w, b.w, c.w);
    *(ushort4*)&W1[idx] = a; *(ushort4*)&W2[idx] = b; *(ushort4*)&W3[idx] = c;
}

__global__ __launch_bounds__(256) void conv_tht(const float* __restrict__ Ths, ushort* __restrict__ ThsT) {
    int idx = blockIdx.x * 256 + threadIdx.x;     // k*4096 + o*64 + i
    int k = idx >> 12, o = (idx >> 6) & 63, i = idx & 63;
    ThsT[idx] = f32_to_bf16(Ths[k * 4096 + i * 64 + o]);
}

// ---------------- static chain GEMM: Y = Ws@B (MODE0) or Y = 2*Ws@B - Cin (MODE1), bf16 MFMA
template <int MODE>
__global__ __launch_bounds__(256) void gemm_s(const ushort* __restrict__ A,    // [2048][2048] bf16
                                              const ushort* __restrict__ BT,   // [512][2048] bf16
                                              const ushort* __restrict__ CinT, // [512][2048] bf16
                                              ushort* __restrict__ YT,         // [512][2048]
                                              ushort* __restrict__ Yo) {       // [2048][512]
    __shared__ char lsA[8192];
    __shared__ char lsB[8192];
    const int t = threadIdx.x;
    const int m0 = blockIdx.x * 64, c0 = blockIdx.y * 64;
    const int lane = t & 63, w = t >> 6, wr = w >> 1, wc = w & 1;
    const int l15 = lane & 15, l4 = lane >> 4;
    f32x4 z = {0.f, 0.f, 0.f, 0.f};
    f32x4 acc[2][2];
    acc[0][0] = z; acc[0][1] = z; acc[1][0] = z; acc[1][1] = z;

    for (int k0 = 0; k0 < 2048; k0 += 64) {
        stage64x64(A + (size_t)m0 * 2048 + k0, 2048, lsA, t);
        stage64x64(BT + (size_t)c0 * 2048 + k0, 2048, lsB, t);
        __syncthreads();
#pragma unroll
        for (int s = 0; s < 2; ++s) {
            const int kb = s * 64 + l4 * 16;
            bf16x8 aF[2], bF[2];
#pragma unroll
            for (int f = 0; f < 2; ++f) {
                aF[f] = fragld(lsA, wr * 32 + f * 16 + l15, kb);
                bF[f] = fragld(lsB, wc * 32 + f * 16 + l15, kb);
            }
#pragma unroll
            for (int i = 0; i < 2; ++i)
#pragma unroll
                for (int j = 0; j < 2; ++j)
                    acc[i][j] = __builtin_amdgcn_mfma_f32_16x16x32_bf16(aF[i], bF[j], acc[i][j], 0, 0, 0);
        }
        __syncthreads();
    }

    ushort* tileo = (ushort*)lsA;   // 64x64 bf16 bounce (last sync already passed)
#pragma unroll
    for (int i = 0; i < 2; ++i)
#pragma unroll
        for (int j = 0; j < 2; ++j) {
            const int lr = wr * 32 + i * 16 + l4 * 4;
            const int lc = wc * 32 + j * 16 + l15;
            float vv[4] = {acc[i][j][0], acc[i][j][1], acc[i][j][2], acc[i][j][3]};
            if (MODE == 1) {
                ushort4 ci = *(const ushort4*)&CinT[(size_t)(c0 + lc) * 2048 + m0 + lr];
                vv[0] = 2.f * vv[0] - bf16_to_f32(ci.x);
                vv[1] = 2.f * vv[1] - bf16_to_f32(ci.y);
                vv[2] = 2.f * vv[2] - bf16_to_f32(ci.z);
                vv[3] = 2.f * vv[3] - bf16_to_f32(ci.w);
            }
            ushort4 p;
            p.x = f32_to_bf16(vv[0]); p.y = f32_to_bf16(vv[1]);
            p.z = f32_to_bf16(vv[2]); p.w = f32_to_bf16(vv[3]);
            *(ushort4*)&YT[(size_t)(c0 + lc) * 2048 + m0 + lr] = p;
            tileo[(lr + 0) * 64 + lc] = p.x;
            tileo[(lr + 1) * 64 + lc] = p.y;
            tileo[(lr + 2) * 64 + lc] = p.z;
            tileo[(lr + 3) * 64 + lc] = p.w;
        }
    __syncthreads();
#pragma unroll
    for (int it = 0; it < 2; ++it) {
        int f = it * 256 + t, row = f >> 3, ch = f & 7;
        uint4 val = *(uint4*)&tileo[row * 64 + ch * 8];
        *(uint4*)&Yo[(size_t)(m0 + row) * 512 + c0 + ch * 8] = val;
    }
}

// ---------------- WaX GEMM, split-3 bf16 (6 products) -> f32 WaXT [512][2048]
__global__ __launch_bounds__(256) void gemm3(const ushort* __restrict__ A1, const ushort* __restrict__ A2,
                                             const ushort* __restrict__ A3,
                                             const ushort* __restrict__ B1, const ushort* __restrict__ B2,
                                             const ushort* __restrict__ B3,
                                             float* __restrict__ WaXT) {
    __shared__ char ls[49152];   // A1,A2,A3,B1,B2,B3 x 8KB
    const int t = threadIdx.x;
    const int m0 = blockIdx.x * 64, c0 = blockIdx.y * 64;
    const int lane = t & 63, w = t >> 6, wr = w >> 1, wc = w & 1;
    const int l15 = lane & 15, l4 = lane >> 4;
    f32x4 z = {0.f, 0.f, 0.f, 0.f};
    f32x4 acc[2][2];
    acc[0][0] = z; acc[0][1] = z; acc[1][0] = z; acc[1][1] = z;

    for (int k0 = 0; k0 < 2048; k0 += 64) {
        stage64x64(A1 + (size_t)m0 * 2048 + k0, 2048, ls + 0 * 8192, t);
        stage64x64(A2 + (size_t)m0 * 2048 + k0, 2048, ls + 1 * 8192, t);
        stage64x64(A3 + (size_t)m0 * 2048 + k0, 2048, ls + 2 * 8192, t);
        stage64x64(B1 + (size_t)c0 * 2048 + k0, 2048, ls + 3 * 8192, t);
        stage64x64(B2 + (size_t)c0 * 2048 + k0, 2048, ls + 4 * 8192, t);
        stage64x64(B3 + (size_t)c0 * 2048 + k0, 2048, ls + 5 * 8192, t);
        __syncthreads();
#pragma unroll
        for (int s = 0; s < 2; ++s) {
            const int kb = s * 64 + l4 * 16;
            bf16x8 aF[2][3], bF[2][3];
#pragma unroll
            for (int f = 0; f < 2; ++f)
#pragma unroll
                for (int m = 0; m < 3; ++m) {
                    aF[f][m] = fragld(ls + m * 8192, wr * 32 + f * 16 + l15, kb);
                    bF[f][m] = fragld(ls + (3 + m) * 8192, wc * 32 + f * 16 + l15, kb);
                }
#pragma unroll
            for (int i = 0; i < 2; ++i)
#pragma unroll
                for (int j = 0; j < 2; ++j) {
                    f32x4 a = acc[i][j];
                    a = __builtin_amdgcn_mfma_f32_16x16x32_bf16(aF[i][0], bF[j][0], a, 0, 0, 0);
                    a = __builtin_amdgcn_mfma_f32_16x16x32_bf16(aF[i][0], bF[j][1], a, 0, 0, 0);
                    a = __builtin_amdgcn_mfma_f32_16x16x32_bf16(aF[i][1], bF[j][0], a, 0, 0, 0);
                    a = __builtin_amdgcn_mfma_f32_16x16x32_bf16(aF[i][0], bF[j][2], a, 0, 0, 0);
                    a = __builtin_amdgcn_mfma_f32_16x16x32_bf16(aF[i][1], bF[j][1], a, 0, 0, 0);
                    a = __builtin_amdgcn_mfma_f32_16x16x32_bf16(aF[i][2], bF[j][0], a, 0, 0, 0);
                    acc[i][j] = a;
                }
        }
        __syncthreads();
    }
#pragma unroll
    for (int i = 0; i < 2; ++i)
#pragma unroll
        for (int j = 0; j < 2; ++j) {
            const int lr = wr * 32 + i * 16 + l4 * 4;
            const int lc = wc * 32 + j * 16 + l15;
            *(f32x4*)&WaXT[(size_t)(c0 + lc) * 2048 + m0 + lr] = acc[i][j];
        }
}

// ---------------- G[b] = WaX^T @ X (f32), partials over 8 n-chunks of 256
__global__ __launch_bounds__(256) void gram(const float* __restrict__ WaXT,
                                            const ushort* __restrict__ XT1, const ushort* __restrict__ XT2,
                                            const ushort* __restrict__ XT3,
                                            float* __restrict__ Gpart) {
    const int b = blockIdx.x, chunk = blockIdx.y;
    __shared__ float Lw[64][68];
    __shared__ float Rx[64][68];
    const int t = threadIdx.x, tx = t & 15, ty = t >> 4;
    float acc[4][4] = {{0.f,0.f,0.f,0.f},{0.f,0.f,0.f,0.f},{0.f,0.f,0.f,0.f},{0.f,0.f,0.f,0.f}};
    for (int sub = 0; sub < 4; ++sub) {
        const int n0 = chunk * 256 + sub * 64;
        if (sub) __syncthreads();
#pragma unroll
        for (int it = 0; it < 4; ++it) {
            int f = it * 256 + t, r = f >> 4, q = (f & 15) * 4;
            size_t a = (size_t)(b * 64 + r) * 2048 + n0 + q;
            *(float4*)&Lw[r][q] = *(const float4*)&WaXT[a];
            ushort4 h1 = *(const ushort4*)&XT1[a];
            ushort4 h2 = *(const ushort4*)&XT2[a];
            ushort4 h3 = *(const ushort4*)&XT3[a];
            Rx[r][q + 0] = bf16_to_f32(h1.x) + bf16_to_f32(h2.x) + bf16_to_f32(h3.x);
            Rx[r][q + 1] = bf16_to_f32(h1.y) + bf16_to_f32(h2.y) + bf16_to_f32(h3.y);
            Rx[r][q + 2] = bf16_to_f32(h1.z) + bf16_to_f32(h2.z) + bf16_to_f32(h3.z);
            Rx[r][q + 3] = bf16_to_f32(h1.w) + bf16_to_f32(h2.w) + bf16_to_f32(h3.w);
        }
        __syncthreads();
        for (int n = 0; n < 64; ++n) {
            float a[4], bb[4];
#pragma unroll
            for (int i = 0; i < 4; ++i) { a[i] = Lw[ty * 4 + i][n]; bb[i] = Rx[tx * 4 + i][n]; }
#pragma unroll
            for (int i = 0; i < 4; ++i)
#pragma unroll
                for (int j = 0; j < 4; ++j) acc[i][j] = fmaf(a[i], bb[j], acc[i][j]);
        }
    }
    float* gp = Gpart + (size_t)(chunk * 8 + b) * 4096;
#pragma unroll
    for (int i = 0; i < 4; ++i) {
        float4 v = make_float4(acc[i][0], acc[i][1], acc[i][2], acc[i][3]);
        *(float4*)&gp[(ty * 4 + i) * 64 + tx * 4] = v;
    }
}

__global__ __launch_bounds__(256) void reduce_g(const float* __restrict__ Gpart, float* __restrict__ G) {
    int idx = blockIdx.x * 256 + threadIdx.x;   // 8*4096
    float s = 0.f;
#pragma unroll
    for (int c = 0; c < 8; ++c) s += Gpart[(size_t)c * 8 * 4096 + idx];
    G[idx] = s;
}

// ---------------- per-batch Chebyshev in 64-space; emits DT = D^T split-2 bf16
__global__ __launch_bounds__(256) void cheb_dt(const float* __restrict__ G, const float* __restrict__ Thd,
                                               ushort* __restrict__ DT1, ushort* __restrict__ DT2) {
    const int b = blockIdx.x;
    __shared__ float Gs[64][68];
    __shared__ float C2s[64][68];
    __shared__ float C3s[64][68];
    const int t = threadIdx.x, tx = t & 15, ty = t >> 4;
    for (int i = t; i < 4096; i += 256) Gs[i >> 6][i & 63] = G[b * 4096 + i];
    __syncthreads();
    const int r0 = ty * 4, c0 = tx * 4;

    float p[4][4] = {{0,0,0,0},{0,0,0,0},{0,0,0,0},{0,0,0,0}};
    for (int k = 0; k < 64; ++k) {
        float ar[4] = {Gs[r0][k], Gs[r0+1][k], Gs[r0+2][k], Gs[r0+3][k]};
        float4 bv = *(const float4*)&Gs[k][c0];
        float br[4] = {bv.x, bv.y, bv.z, bv.w};
#pragma unroll
        for (int i = 0; i < 4; ++i)
#pragma unroll
            for (int j = 0; j < 4; ++j) p[i][j] = fmaf(ar[i], br[j], p[i][j]);
    }
#pragma unroll
    for (int i = 0; i < 4; ++i)
#pragma unroll
        for (int j = 0; j < 4; ++j)
            C2s[r0+i][c0+j] = 2.f * p[i][j] - ((r0+i) == (c0+j) ? 1.f : 0.f);
    __syncthreads();

    float q[4][4] = {{0,0,0,0},{0,0,0,0},{0,0,0,0},{0,0,0,0}};
    for (int k = 0; k < 64; ++k) {
        float ar[4] = {Gs[r0][k], Gs[r0+1][k], Gs[r0+2][k], Gs[r0+3][k]};
        float4 bv = *(const float4*)&C2s[k][c0];
        float br[4] = {bv.x, bv.y, bv.z, bv.w};
#pragma unroll
        for (int i = 0; i < 4; ++i)
#pragma unroll
            for (int j = 0; j < 4; ++j) q[i][j] = fmaf(ar[i], br[j], q[i][j]);
    }
#pragma unroll
    for (int i = 0; i < 4; ++i)
#pragma unroll
        for (int j = 0; j < 4; ++j)
            C3s[r0+i][c0+j] = 2.f * q[i][j] - Gs[r0+i][c0+j];
    __syncthreads();

    float d[4][4];
#pragma unroll
    for (int i = 0; i < 4; ++i) {
        float4 t0 = *(const float4*)&Thd[(r0+i) * 64 + c0];
        d[i][0] = t0.x; d[i][1] = t0.y; d[i][2] = t0.z; d[i][3] = t0.w;
    }
    for (int k = 0; k < 64; ++k) {
        float4 t1 = *(const float4*)&Thd[4096 + k * 64 + c0];
        float4 t2 = *(const float4*)&Thd[8192 + k * 64 + c0];
        float4 t3 = *(const float4*)&Thd[12288 + k * 64 + c0];
        float a1[4] = {Gs[r0][k], Gs[r0+1][k], Gs[r0+2][k], Gs[r0+3][k]};
        float a2[4] = {C2s[r0][k], C2s[r0+1][k], C2s[r0+2][k], C2s[r0+3][k]};
        float a3[4] = {C3s[r0][k], C3s[r0+1][k], C3s[r0+2][k], C3s[r0+3][k]};
        float b1[4] = {t1.x, t1.y, t1.z, t1.w};
        float b2[4] = {t2.x, t2.y, t2.z, t2.w};
        float b3[4] = {t3.x, t3.y, t3.z, t3.w};
#pragma unroll
        for (int i = 0; i < 4; ++i)
#pragma unroll
            for (int j = 0; j < 4; ++j) {
                d[i][j] = fmaf(a1[i], b1[j], d[i][j]);
                d[i][j] = fmaf(a2[i], b2[j], d[i][j]);
                d[i][j] = fmaf(a3[i], b3[j], d[i][j]);
            }
    }
    __syncthreads();
#pragma unroll
    for (int i = 0; i < 4; ++i)
#pragma unroll
        for (int j = 0; j < 4; ++j) Gs[r0 + i][c0 + j] = d[i][j];
    __syncthreads();
#pragma unroll
    for (int it = 0; it < 16; ++it) {
        int idx = it * 256 + t;          // o*64 + i
        int o = idx >> 6, ii = idx & 63;
        float v = Gs[ii][o];
        ushort h1, h2;
        split2(v, h1, h2);
        DT1[b * 4096 + idx] = h1;
        DT2[b * 4096 + idx] = h2;
    }
}

// ---------------- fused epilogue: out = relu(sum_k ThsT_k @ TkX) + relu(DT @ X), MFMA K=64
__global__ __launch_bounds__(256) void ep_fused(const ushort* __restrict__ ThsT,
                                                const ushort* __restrict__ DT1, const ushort* __restrict__ DT2,
                                                const ushort* __restrict__ X1o, const ushort* __restrict__ X2o,
                                                const ushort* __restrict__ Y1o, const ushort* __restrict__ Y2o,
                                                const ushort* __restrict__ Y3o,
                                                float* __restrict__ out) {
    __shared__ char ls[65536];   // slots: 0=X1,1=Y1/DT1,2=Y2/DT2,3=Y3/X2,4..7=ThsT0..3
    const int b = blockIdx.y, n0 = blockIdx.x * 64;
    const int t = threadIdx.x, lane = t & 63, w = t >> 6, wr = w >> 1, wc = w & 1;
    const int l15 = lane & 15, l4 = lane >> 4;
    stage64x64(X1o + (size_t)n0 * 512 + b * 64, 512, ls + 0 * 8192, t);
    stage64x64(Y1o + (size_t)n0 * 512 + b * 64, 512, ls + 1 * 8192, t);
    stage64x64(Y2o + (size_t)n0 * 512 + b * 64, 512, ls + 2 * 8192, t);
    stage64x64(Y3o + (size_t)n0 * 512 + b * 64, 512, ls + 3 * 8192, t);
    stage64x64(ThsT + 0 * 4096, 64, ls + 4 * 8192, t);
    stage64x64(ThsT + 1 * 4096, 64, ls + 5 * 8192, t);
    stage64x64(ThsT + 2 * 4096, 64, ls + 6 * 8192, t);
    stage64x64(ThsT + 3 * 4096, 64, ls + 7 * 8192, t);
    __syncthreads();
    f32x4 z = {0.f, 0.f, 0.f, 0.f};
    f32x4 as[2][2], ad[2][2];
    as[0][0] = z; as[0][1] = z; as[1][0] = z; as[1][1] = z;
    ad[0][0] = z; ad[0][1] = z; ad[1][0] = z; ad[1][1] = z;
#pragma unroll
    for (int s = 0; s < 2; ++s) {
        const int kb = s * 64 + l4 * 16;
#pragma unroll
        for (int p = 0; p < 4; ++p) {
            bf16x8 aF[2], bF[2];
#pragma unroll
            for (int f = 0; f < 2; ++f) {
                aF[f] = fragld(ls + (4 + p) * 8192, wr * 32 + f * 16 + l15, kb);
                bF[f] = fragld(ls + p * 8192, wc * 32 + f * 16 + l15, kb);
            }
#pragma unroll
            for (int i = 0; i < 2; ++i)
#pragma unroll
                for (int j = 0; j < 2; ++j)
                    as[i][j] = __builtin_amdgcn_mfma_f32_16x16x32_bf16(aF[i], bF[j], as[i][j], 0, 0, 0);
        }
    }
    __syncthreads();
    stage64x64(DT1 + b * 4096, 64, ls + 1 * 8192, t);
    stage64x64(DT2 + b * 4096, 64, ls + 2 * 8192, t);
    stage64x64(X2o + (size_t)n0 * 512 + b * 64, 512, ls + 3 * 8192, t);
    __syncthreads();
#pragma unroll
    for (int s = 0; s < 2; ++s) {
        const int kb = s * 64 + l4 * 16;
        bf16x8 a1[2], a2[2], b0[2], b3[2];
#pragma unroll
        for (int f = 0; f < 2; ++f) {
            a1[f] = fragld(ls + 1 * 8192, wr * 32 + f * 16 + l15, kb);
            a2[f] = fragld(ls + 2 * 8192, wr * 32 + f * 16 + l15, kb);
            b0[f] = fragld(ls + 0 * 8192, wc * 32 + f * 16 + l15, kb);
            b3[f] = fragld(ls + 3 * 8192, wc * 32 + f * 16 + l15, kb);
        }
#pragma unroll
        for (int i = 0; i < 2; ++i)
#pragma unroll
            for (int j = 0; j < 2; ++j) {
                f32x4 a = ad[i][j];
                a = __builtin_amdgcn_mfma_f32_16x16x32_bf16(a1[i], b0[j], a, 0, 0, 0);
                a = __builtin_amdgcn_mfma_f32_16x16x32_bf16(a1[i], b3[j], a, 0, 0, 0);
                a = __builtin_amdgcn_mfma_f32_16x16x32_bf16(a2[i], b0[j], a, 0, 0, 0);
                ad[i][j] = a;
            }
    }
#pragma unroll
    for (int i = 0; i < 2; ++i)
#pragma unroll
        for (int j = 0; j < 2; ++j) {
            const int ob = wr * 32 + i * 16 + l4 * 4;
            const int nn = wc * 32 + j * 16 + l15;
            float4 o4;
            o4.x = fmaxf(as[i][j][0], 0.f) + fmaxf(ad[i][j][0], 0.f);
            o4.y = fmaxf(as[i][j][1], 0.f) + fmaxf(ad[i][j][1], 0.f);
            o4.z = fmaxf(as[i][j][2], 0.f) + fmaxf(ad[i][j][2], 0.f);
            o4.w = fmaxf(as[i][j][3], 0.f) + fmaxf(ad[i][j][3], 0.f);
            *(float4*)&out[((size_t)b * 2048 + n0 + nn) * 64 + ob] = o4;
        }
}

extern "C" void kernel_launch(void* const* d_in, const int* in_sizes, int n_in,
                              void* d_out, int out_size, void* d_ws, size_t ws_size,
                              hipStream_t stream) {
    const float* X   = (const float*)d_in[0];
    const float* Ws  = (const float*)d_in[1];
    const float* Wa  = (const float*)d_in[2];
    const float* Ths = (const float*)d_in[3];
    const float* Thd = (const float*)d_in[4];

    char* p = (char*)d_ws;
    auto alloc = [&](size_t bytes) { char* r = p; p += (bytes + 255) & ~(size_t)255; return r; };
    ushort* XT1 = (ushort*)alloc(512ull * 2048 * 2);
    ushort* XT2 = (ushort*)alloc(512ull * 2048 * 2);
    ushort* XT3 = (ushort*)alloc(512ull * 2048 * 2);
    ushort* X1o = (ushort*)alloc(2048ull * 512 * 2);
    ushort* X2o = (ushort*)alloc(2048ull * 512 * 2);
    ushort* Ws16 = (ushort*)alloc(2048ull * 2048 * 2);
    ushort* Wa1 = (ushort*)alloc(2048ull * 2048 * 2);
    ushort* Wa2 = (ushort*)alloc(2048ull * 2048 * 2);
    ushort* Wa3 = (ushort*)alloc(2048ull * 2048 * 2);
    ushort* Y1T = (ushort*)alloc(512ull * 2048 * 2);
    ushort* Y2T = (ushort*)alloc(512ull * 2048 * 2);
    ushort* Y3T = (ushort*)alloc(512ull * 2048 * 2);
    ushort* Y1o = (ushort*)alloc(2048ull * 512 * 2);
    ushort* Y2o = (ushort*)alloc(2048ull * 512 * 2);
    ushort* Y3o = (ushort*)alloc(2048ull * 512 * 2);
    float*  Gpart = (float*)alloc(8ull * 8 * 4096 * 4);
    float*  G = (float*)alloc(8ull * 4096 * 4);
    ushort* DT1 = (ushort*)alloc(8ull * 4096 * 2);
    ushort* DT2 = (ushort*)alloc(8ull * 4096 * 2);
    ushort* ThsT = (ushort*)alloc(4ull * 4096 * 2);
    if ((size_t)(p - (char*)d_ws) > ws_size) return;   // visible failure if ws too small
    float* WaXT = (float*)d_out;                       // 4MB scratch, overwritten by ep_fused later

    prep_xt<<<dim3(32, 8), 256, 0, stream>>>(X, XT1, XT2, XT3, X1o, X2o);
    conv_ws<<<4096, 256, 0, stream>>>(Ws, Ws16);
    conv_wa<<<4096, 256, 0, stream>>>(Wa, Wa1, Wa2, Wa3);
    conv_tht<<<64, 256, 0, stream>>>(Ths, ThsT);

    gemm_s<0><<<dim3(32, 8), 256, 0, stream>>>(Ws16, XT1, nullptr, Y1T, Y1o);
    gemm_s<1><<<dim3(32, 8), 256, 0, stream>>>(Ws16, Y1T, XT1, Y2T, Y2o);
    gemm_s<1><<<dim3(32, 8), 256, 0, stream>>>(Ws16, Y2T, Y1T, Y3T, Y3o);

    gemm3<<<dim3(32, 8), 256, 0, stream>>>(Wa1, Wa2, Wa3, XT1, XT2, XT3, WaXT);
    gram<<<dim3(8, 8), 256, 0, stream>>>(WaXT, XT1, XT2, XT3, Gpart);
    reduce_g<<<128, 256, 0, stream>>>(Gpart, G);
    cheb_dt<<<8, 256, 0, stream>>>(G, Thd, DT1, DT2);

    ep_fused<<<dim3(32, 8), 256, 0, stream>>>(ThsT, DT1, DT2, X1o, X2o, Y1o, Y2o, Y3o, (float*)d_out);
}

// Round 3
// 140.282 us; speedup vs baseline: 3.8533x; 1.2681x over previous
//
#include <hip/hip_runtime.h>

typedef __attribute__((ext_vector_type(8))) short bf16x8;
typedef __attribute__((ext_vector_type(4))) float f32x4;

__device__ __forceinline__ ushort f32_to_bf16(float f) {
    union { float f; unsigned u; } v; v.f = f;
    unsigned b = v.u + 0x7FFF + ((v.u >> 16) & 1);
    return (ushort)(b >> 16);
}
__device__ __forceinline__ float bf16_to_f32(ushort h) {
    union { unsigned u; float f; } v; v.u = ((unsigned)h) << 16;
    return v.f;
}
__device__ __forceinline__ void split2(float x, ushort& a, ushort& b) {
    a = f32_to_bf16(x); float r1 = x - bf16_to_f32(a);
    b = f32_to_bf16(r1);
}

// Stage a 64-row x 128-byte tile from global (row-major) into 8KB LDS with XOR
// swizzle applied via the GLOBAL source address (linear LDS dest, rule #21);
// read side (fragld) applies the same XOR. t256 in [0,256), 2 chunks/thread.
__device__ __forceinline__ void stage64x64(const ushort* gsrc, int row_stride_elems,
                                           char* lds, int t256) {
    const char* gb = (const char*)gsrc;
    const int rs = row_stride_elems * 2;
#pragma unroll
    for (int j = 0; j < 2; ++j) {
        int o = (j * 256 + t256) * 16;
        int row = o >> 7;
        int col = (o & 127) ^ ((row & 7) << 4);
        __builtin_amdgcn_global_load_lds(
            (const __attribute__((address_space(1))) unsigned int*)(gb + row * rs + col),
            (__attribute__((address_space(3))) unsigned int*)(lds + o), 16, 0, 0);
    }
}

__device__ __forceinline__ bf16x8 fragld(const char* lds, int row, int kbyte) {
    return *(const bf16x8*)(lds + (row << 7) + (kbyte ^ ((row & 7) << 4)));
}

// ---------------- prep: X (B,2048,64) f32 -> XT split2 [512][2048], orig split2 [2048][512]
__global__ __launch_bounds__(256) void prep_xt(const float* __restrict__ X,
                                               ushort* __restrict__ XT1, ushort* __restrict__ XT2,
                                               ushort* __restrict__ X1o, ushort* __restrict__ X2o) {
    const int b = blockIdx.y, n0 = blockIdx.x * 64;
    __shared__ float tile[64][68];
    const int t = threadIdx.x;
#pragma unroll
    for (int it = 0; it < 4; ++it) {
        int f = it * 256 + t, r = f >> 4, q = (f & 15) * 4;
        float4 v = *(const float4*)&X[((size_t)b * 2048 + n0 + r) * 64 + q];
        tile[r][q + 0] = v.x; tile[r][q + 1] = v.y; tile[r][q + 2] = v.z; tile[r][q + 3] = v.w;
    }
    __syncthreads();
#pragma unroll
    for (int it = 0; it < 4; ++it) {   // T-layout: row = b*64+c, cols n
        int f = it * 256 + t, c = f >> 4, q = (f & 15) * 4;
        ushort4 h1, h2;
        split2(tile[q + 0][c], h1.x, h2.x); split2(tile[q + 1][c], h1.y, h2.y);
        split2(tile[q + 2][c], h1.z, h2.z); split2(tile[q + 3][c], h1.w, h2.w);
        size_t a = (size_t)(b * 64 + c) * 2048 + n0 + q;
        *(ushort4*)&XT1[a] = h1; *(ushort4*)&XT2[a] = h2;
    }
#pragma unroll
    for (int it = 0; it < 4; ++it) {   // orig layout: row n, cols bc
        int f = it * 256 + t, n = f >> 4, q = (f & 15) * 4;
        ushort4 h1, h2;
        split2(tile[n][q + 0], h1.x, h2.x); split2(tile[n][q + 1], h1.y, h2.y);
        split2(tile[n][q + 2], h1.z, h2.z); split2(tile[n][q + 3], h1.w, h2.w);
        size_t a = (size_t)(n0 + n) * 512 + b * 64 + q;
        *(ushort4*)&X1o[a] = h1; *(ushort4*)&X2o[a] = h2;
    }
}

__global__ __launch_bounds__(256) void conv_ws(const float* __restrict__ W, ushort* __restrict__ W1) {
    size_t idx = ((size_t)blockIdx.x * 256 + threadIdx.x) * 4;
    float4 v = *(const float4*)&W[idx];
    ushort4 a;
    a.x = f32_to_bf16(v.x); a.y = f32_to_bf16(v.y); a.z = f32_to_bf16(v.z); a.w = f32_to_bf16(v.w);
    *(ushort4*)&W1[idx] = a;
}

__global__ __launch_bounds__(256) void conv_wa(const float* __restrict__ W, ushort* __restrict__ W1,
                                               ushort* __restrict__ W2) {
    size_t idx = ((size_t)blockIdx.x * 256 + threadIdx.x) * 4;
    float4 v = *(const float4*)&W[idx];
    ushort4 a, b;
    split2(v.x, a.x, b.x); split2(v.y, a.y, b.y);
    split2(v.z, a.z, b.z); split2(v.w, a.w, b.w);
    *(ushort4*)&W1[idx] = a; *(ushort4*)&W2[idx] = b;
}

__global__ __launch_bounds__(256) void conv_tht(const float* __restrict__ Ths, ushort* __restrict__ ThsT) {
    int idx = blockIdx.x * 256 + threadIdx.x;     // k*4096 + o*64 + i
    int k = idx >> 12, o = (idx >> 6) & 63, i = idx & 63;
    ThsT[idx] = f32_to_bf16(Ths[k * 4096 + i * 64 + o]);
}

// ---------------- static chain GEMM, 512 threads, in-block K-split (waves 0-3: K lo, 4-7: K hi)
template <int MODE>
__global__ __launch_bounds__(512) void gemm_s(const ushort* __restrict__ A,    // [2048][2048] bf16
                                              const ushort* __restrict__ BT,   // [512][2048] bf16
                                              const ushort* __restrict__ CinT, // [512][2048] bf16
                                              ushort* __restrict__ YT,         // [512][2048]
                                              ushort* __restrict__ Yo) {       // [2048][512]
    __shared__ char ls[32768];
    const int t = threadIdx.x;
    const int g = t >> 8, t256 = t & 255;
    const int m0 = blockIdx.x * 64, c0 = blockIdx.y * 64;
    const int lane = t & 63;
    const int wg = (t >> 6) & 3, wr = wg >> 1, wc = wg & 1;
    const int l15 = lane & 15, l4 = lane >> 4;
    char* lsA = ls + g * 16384;
    char* lsB = lsA + 8192;
    const size_t kbase = (size_t)g * 1024;

    f32x4 z = {0.f, 0.f, 0.f, 0.f};
    f32x4 acc[2][2];
    acc[0][0] = z; acc[0][1] = z; acc[1][0] = z; acc[1][1] = z;

    for (int k0 = 0; k0 < 1024; k0 += 64) {
        stage64x64(A + (size_t)m0 * 2048 + kbase + k0, 2048, lsA, t256);
        stage64x64(BT + (size_t)c0 * 2048 + kbase + k0, 2048, lsB, t256);
        __syncthreads();
#pragma unroll
        for (int s = 0; s < 2; ++s) {
            const int kb = s * 64 + l4 * 16;
            bf16x8 aF[2], bF[2];
#pragma unroll
            for (int f = 0; f < 2; ++f) {
                aF[f] = fragld(lsA, wr * 32 + f * 16 + l15, kb);
                bF[f] = fragld(lsB, wc * 32 + f * 16 + l15, kb);
            }
#pragma unroll
            for (int i = 0; i < 2; ++i)
#pragma unroll
                for (int j = 0; j < 2; ++j)
                    acc[i][j] = __builtin_amdgcn_mfma_f32_16x16x32_bf16(aF[i], bF[j], acc[i][j], 0, 0, 0);
        }
        __syncthreads();
    }

    // cross-group reduce in LDS (pad-65 to dodge bank conflicts), then epilogue by group 1
    float* red = (float*)ls;                       // 64*65*4 = 16640 B
    ushort* tileo = (ushort*)(ls + 17408);         // 8 KB bounce for Yo
    if (g == 0) {
#pragma unroll
        for (int i = 0; i < 2; ++i)
#pragma unroll
            for (int j = 0; j < 2; ++j) {
                const int lrb = wr * 32 + i * 16 + l4 * 4;
                const int lc = wc * 32 + j * 16 + l15;
#pragma unroll
                for (int r = 0; r < 4; ++r) red[(lrb + r) * 65 + lc] = acc[i][j][r];
            }
    }
    __syncthreads();
    if (g == 1) {
#pragma unroll
        for (int i = 0; i < 2; ++i)
#pragma unroll
            for (int j = 0; j < 2; ++j) {
                const int lrb = wr * 32 + i * 16 + l4 * 4;
                const int lc = wc * 32 + j * 16 + l15;
                float vv[4];
#pragma unroll
                for (int r = 0; r < 4; ++r) vv[r] = red[(lrb + r) * 65 + lc] + acc[i][j][r];
                if (MODE == 1) {
                    ushort4 ci = *(const ushort4*)&CinT[(size_t)(c0 + lc) * 2048 + m0 + lrb];
                    vv[0] = 2.f * vv[0] - bf16_to_f32(ci.x);
                    vv[1] = 2.f * vv[1] - bf16_to_f32(ci.y);
                    vv[2] = 2.f * vv[2] - bf16_to_f32(ci.z);
                    vv[3] = 2.f * vv[3] - bf16_to_f32(ci.w);
                }
                ushort4 p;
                p.x = f32_to_bf16(vv[0]); p.y = f32_to_bf16(vv[1]);
                p.z = f32_to_bf16(vv[2]); p.w = f32_to_bf16(vv[3]);
                *(ushort4*)&YT[(size_t)(c0 + lc) * 2048 + m0 + lrb] = p;
                tileo[(lrb + 0) * 64 + lc] = p.x;
                tileo[(lrb + 1) * 64 + lc] = p.y;
                tileo[(lrb + 2) * 64 + lc] = p.z;
                tileo[(lrb + 3) * 64 + lc] = p.w;
            }
    }
    __syncthreads();
    {   // all 512 threads: copy bounce -> Yo [2048][512]
        int row = t >> 3, ch = t & 7;
        *(uint4*)&Yo[(size_t)(m0 + row) * 512 + c0 + ch * 8] = *(uint4*)&tileo[row * 64 + ch * 8];
    }
}

// ---------------- WaX GEMM, split-2 bf16 (3 products), 512 threads, in-block K-split
__global__ __launch_bounds__(512) void gemm3(const ushort* __restrict__ A1, const ushort* __restrict__ A2,
                                             const ushort* __restrict__ B1, const ushort* __restrict__ B2,
                                             float* __restrict__ WaXT) {
    __shared__ char ls[65536];   // per group: A1,A2,B1,B2 x 8KB
    const int t = threadIdx.x;
    const int g = t >> 8, t256 = t & 255;
    const int m0 = blockIdx.x * 64, c0 = blockIdx.y * 64;
    const int lane = t & 63;
    const int wg = (t >> 6) & 3, wr = wg >> 1, wc = wg & 1;
    const int l15 = lane & 15, l4 = lane >> 4;
    char* base = ls + g * 32768;
    const size_t kbase = (size_t)g * 1024;

    f32x4 z = {0.f, 0.f, 0.f, 0.f};
    f32x4 acc[2][2];
    acc[0][0] = z; acc[0][1] = z; acc[1][0] = z; acc[1][1] = z;

    for (int k0 = 0; k0 < 1024; k0 += 64) {
        stage64x64(A1 + (size_t)m0 * 2048 + kbase + k0, 2048, base + 0 * 8192, t256);
        stage64x64(A2 + (size_t)m0 * 2048 + kbase + k0, 2048, base + 1 * 8192, t256);
        stage64x64(B1 + (size_t)c0 * 2048 + kbase + k0, 2048, base + 2 * 8192, t256);
        stage64x64(B2 + (size_t)c0 * 2048 + kbase + k0, 2048, base + 3 * 8192, t256);
        __syncthreads();
#pragma unroll
        for (int s = 0; s < 2; ++s) {
            const int kb = s * 64 + l4 * 16;
            bf16x8 a1F[2], a2F[2], b1F[2], b2F[2];
#pragma unroll
            for (int f = 0; f < 2; ++f) {
                const int ar = wr * 32 + f * 16 + l15;
                const int br = wc * 32 + f * 16 + l15;
                a1F[f] = fragld(base + 0 * 8192, ar, kb);
                a2F[f] = fragld(base + 1 * 8192, ar, kb);
                b1F[f] = fragld(base + 2 * 8192, br, kb);
                b2F[f] = fragld(base + 3 * 8192, br, kb);
            }
#pragma unroll
            for (int i = 0; i < 2; ++i)
#pragma unroll
                for (int j = 0; j < 2; ++j) {
                    f32x4 a = acc[i][j];
                    a = __builtin_amdgcn_mfma_f32_16x16x32_bf16(a1F[i], b1F[j], a, 0, 0, 0);
                    a = __builtin_amdgcn_mfma_f32_16x16x32_bf16(a1F[i], b2F[j], a, 0, 0, 0);
                    a = __builtin_amdgcn_mfma_f32_16x16x32_bf16(a2F[i], b1F[j], a, 0, 0, 0);
                    acc[i][j] = a;
                }
        }
        __syncthreads();
    }

    float* red = (float*)ls;
    if (g == 0) {
#pragma unroll
        for (int i = 0; i < 2; ++i)
#pragma unroll
            for (int j = 0; j < 2; ++j) {
                const int lrb = wr * 32 + i * 16 + l4 * 4;
                const int lc = wc * 32 + j * 16 + l15;
#pragma unroll
                for (int r = 0; r < 4; ++r) red[(lrb + r) * 65 + lc] = acc[i][j][r];
            }
    }
    __syncthreads();
    if (g == 1) {
#pragma unroll
        for (int i = 0; i < 2; ++i)
#pragma unroll
            for (int j = 0; j < 2; ++j) {
                const int lrb = wr * 32 + i * 16 + l4 * 4;
                const int lc = wc * 32 + j * 16 + l15;
                f32x4 v;
#pragma unroll
                for (int r = 0; r < 4; ++r) v[r] = red[(lrb + r) * 65 + lc] + acc[i][j][r];
                *(f32x4*)&WaXT[(size_t)(c0 + lc) * 2048 + m0 + lrb] = v;
            }
    }
}

// ---------------- G[b] = WaX^T @ X (f32), partials over 8 n-chunks of 256
__global__ __launch_bounds__(256) void gram(const float* __restrict__ WaXT,
                                            const ushort* __restrict__ XT1, const ushort* __restrict__ XT2,
                                            float* __restrict__ Gpart) {
    const int b = blockIdx.x, chunk = blockIdx.y;
    __shared__ float Lw[64][68];
    __shared__ float Rx[64][68];
    const int t = threadIdx.x, tx = t & 15, ty = t >> 4;
    float acc[4][4] = {{0.f,0.f,0.f,0.f},{0.f,0.f,0.f,0.f},{0.f,0.f,0.f,0.f},{0.f,0.f,0.f,0.f}};
    for (int sub = 0; sub < 4; ++sub) {
        const int n0 = chunk * 256 + sub * 64;
        if (sub) __syncthreads();
#pragma unroll
        for (int it = 0; it < 4; ++it) {
            int f = it * 256 + t, r = f >> 4, q = (f & 15) * 4;
            size_t a = (size_t)(b * 64 + r) * 2048 + n0 + q;
            *(float4*)&Lw[r][q] = *(const float4*)&WaXT[a];
            ushort4 h1 = *(const ushort4*)&XT1[a];
            ushort4 h2 = *(const ushort4*)&XT2[a];
            Rx[r][q + 0] = bf16_to_f32(h1.x) + bf16_to_f32(h2.x);
            Rx[r][q + 1] = bf16_to_f32(h1.y) + bf16_to_f32(h2.y);
            Rx[r][q + 2] = bf16_to_f32(h1.z) + bf16_to_f32(h2.z);
            Rx[r][q + 3] = bf16_to_f32(h1.w) + bf16_to_f32(h2.w);
        }
        __syncthreads();
        for (int n = 0; n < 64; ++n) {
            float a[4], bb[4];
#pragma unroll
            for (int i = 0; i < 4; ++i) { a[i] = Lw[ty * 4 + i][n]; bb[i] = Rx[tx * 4 + i][n]; }
#pragma unroll
            for (int i = 0; i < 4; ++i)
#pragma unroll
                for (int j = 0; j < 4; ++j) acc[i][j] = fmaf(a[i], bb[j], acc[i][j]);
        }
    }
    float* gp = Gpart + (size_t)(chunk * 8 + b) * 4096;
#pragma unroll
    for (int i = 0; i < 4; ++i)
        *(float4*)&gp[(ty * 4 + i) * 64 + tx * 4] =
            make_float4(acc[i][0], acc[i][1], acc[i][2], acc[i][3]);
}

__global__ __launch_bounds__(256) void reduce_g(const float* __restrict__ Gpart, float* __restrict__ G) {
    int idx = blockIdx.x * 256 + threadIdx.x;   // 8*4096
    float s = 0.f;
#pragma unroll
    for (int c = 0; c < 8; ++c) s += Gpart[(size_t)c * 8 * 4096 + idx];
    G[idx] = s;
}

// ---------------- per-batch Chebyshev in 64-space; emits DT = D^T split-2 bf16
__global__ __launch_bounds__(256) void cheb_dt(const float* __restrict__ G, const float* __restrict__ Thd,
                                               ushort* __restrict__ DT1, ushort* __restrict__ DT2) {
    const int b = blockIdx.x;
    __shared__ float Gs[64][68];
    __shared__ float C2s[64][68];
    __shared__ float C3s[64][68];
    const int t = threadIdx.x, tx = t & 15, ty = t >> 4;
    for (int i = t; i < 4096; i += 256) Gs[i >> 6][i & 63] = G[b * 4096 + i];
    __syncthreads();
    const int r0 = ty * 4, c0 = tx * 4;

    float p[4][4] = {{0,0,0,0},{0,0,0,0},{0,0,0,0},{0,0,0,0}};
    for (int k = 0; k < 64; ++k) {
        float ar[4] = {Gs[r0][k], Gs[r0+1][k], Gs[r0+2][k], Gs[r0+3][k]};
        float4 bv = *(const float4*)&Gs[k][c0];
        float br[4] = {bv.x, bv.y, bv.z, bv.w};
#pragma unroll
        for (int i = 0; i < 4; ++i)
#pragma unroll
            for (int j = 0; j < 4; ++j) p[i][j] = fmaf(ar[i], br[j], p[i][j]);
    }
#pragma unroll
    for (int i = 0; i < 4; ++i)
#pragma unroll
        for (int j = 0; j < 4; ++j)
            C2s[r0+i][c0+j] = 2.f * p[i][j] - ((r0+i) == (c0+j) ? 1.f : 0.f);
    __syncthreads();

    float q[4][4] = {{0,0,0,0},{0,0,0,0},{0,0,0,0},{0,0,0,0}};
    for (int k = 0; k < 64; ++k) {
        float ar[4] = {Gs[r0][k], Gs[r0+1][k], Gs[r0+2][k], Gs[r0+3][k]};
        float4 bv = *(const float4*)&C2s[k][c0];
        float br[4] = {bv.x, bv.y, bv.z, bv.w};
#pragma unroll
        for (int i = 0; i < 4; ++i)
#pragma unroll
            for (int j = 0; j < 4; ++j) q[i][j] = fmaf(ar[i], br[j], q[i][j]);
    }
#pragma unroll
    for (int i = 0; i < 4; ++i)
#pragma unroll
        for (int j = 0; j < 4; ++j)
            C3s[r0+i][c0+j] = 2.f * q[i][j] - Gs[r0+i][c0+j];
    __syncthreads();

    float d[4][4];
#pragma unroll
    for (int i = 0; i < 4; ++i) {
        float4 t0 = *(const float4*)&Thd[(r0+i) * 64 + c0];
        d[i][0] = t0.x; d[i][1] = t0.y; d[i][2] = t0.z; d[i][3] = t0.w;
    }
    for (int k = 0; k < 64; ++k) {
        float4 t1 = *(const float4*)&Thd[4096 + k * 64 + c0];
        float4 t2 = *(const float4*)&Thd[8192 + k * 64 + c0];
        float4 t3 = *(const float4*)&Thd[12288 + k * 64 + c0];
        float a1[4] = {Gs[r0][k], Gs[r0+1][k], Gs[r0+2][k], Gs[r0+3][k]};
        float a2[4] = {C2s[r0][k], C2s[r0+1][k], C2s[r0+2][k], C2s[r0+3][k]};
        float a3[4] = {C3s[r0][k], C3s[r0+1][k], C3s[r0+2][k], C3s[r0+3][k]};
        float b1[4] = {t1.x, t1.y, t1.z, t1.w};
        float b2[4] = {t2.x, t2.y, t2.z, t2.w};
        float b3[4] = {t3.x, t3.y, t3.z, t3.w};
#pragma unroll
        for (int i = 0; i < 4; ++i)
#pragma unroll
            for (int j = 0; j < 4; ++j) {
                d[i][j] = fmaf(a1[i], b1[j], d[i][j]);
                d[i][j] = fmaf(a2[i], b2[j], d[i][j]);
                d[i][j] = fmaf(a3[i], b3[j], d[i][j]);
            }
    }
    __syncthreads();
#pragma unroll
    for (int i = 0; i < 4; ++i)
#pragma unroll
        for (int j = 0; j < 4; ++j) Gs[r0 + i][c0 + j] = d[i][j];
    __syncthreads();
#pragma unroll
    for (int it = 0; it < 16; ++it) {
        int idx = it * 256 + t;          // o*64 + i
        int o = idx >> 6, ii = idx & 63;
        ushort h1, h2;
        split2(Gs[ii][o], h1, h2);
        DT1[b * 4096 + idx] = h1;
        DT2[b * 4096 + idx] = h2;
    }
}

// ---------------- fused epilogue: out = relu(sum_k ThsT_k @ TkX) + relu(DT @ X), MFMA K=64
__global__ __launch_bounds__(256) void ep_fused(const ushort* __restrict__ ThsT,
                                                const ushort* __restrict__ DT1, const ushort* __restrict__ DT2,
                                                const ushort* __restrict__ X1o, const ushort* __restrict__ X2o,
                                                const ushort* __restrict__ Y1o, const ushort* __restrict__ Y2o,
                                                const ushort* __restrict__ Y3o,
                                                float* __restrict__ out) {
    __shared__ char ls[65536];   // slots: 0=X1,1=Y1/DT1,2=Y2/DT2,3=Y3/X2,4..7=ThsT0..3
    const int b = blockIdx.y, n0 = blockIdx.x * 64;
    const int t = threadIdx.x, lane = t & 63, w = t >> 6, wr = w >> 1, wc = w & 1;
    const int l15 = lane & 15, l4 = lane >> 4;
    stage64x64(X1o + (size_t)n0 * 512 + b * 64, 512, ls + 0 * 8192, t);
    stage64x64(Y1o + (size_t)n0 * 512 + b * 64, 512, ls + 1 * 8192, t);
    stage64x64(Y2o + (size_t)n0 * 512 + b * 64, 512, ls + 2 * 8192, t);
    stage64x64(Y3o + (size_t)n0 * 512 + b * 64, 512, ls + 3 * 8192, t);
    stage64x64(ThsT + 0 * 4096, 64, ls + 4 * 8192, t);
    stage64x64(ThsT + 1 * 4096, 64, ls + 5 * 8192, t);
    stage64x64(ThsT + 2 * 4096, 64, ls + 6 * 8192, t);
    stage64x64(ThsT + 3 * 4096, 64, ls + 7 * 8192, t);
    __syncthreads();
    f32x4 z = {0.f, 0.f, 0.f, 0.f};
    f32x4 as[2][2], ad[2][2];
    as[0][0] = z; as[0][1] = z; as[1][0] = z; as[1][1] = z;
    ad[0][0] = z; ad[0][1] = z; ad[1][0] = z; ad[1][1] = z;
#pragma unroll
    for (int s = 0; s < 2; ++s) {
        const int kb = s * 64 + l4 * 16;
#pragma unroll
        for (int p = 0; p < 4; ++p) {
            bf16x8 aF[2], bF[2];
#pragma unroll
            for (int f = 0; f < 2; ++f) {
                aF[f] = fragld(ls + (4 + p) * 8192, wr * 32 + f * 16 + l15, kb);
                bF[f] = fragld(ls + p * 8192, wc * 32 + f * 16 + l15, kb);
            }
#pragma unroll
            for (int i = 0; i < 2; ++i)
#pragma unroll
                for (int j = 0; j < 2; ++j)
                    as[i][j] = __builtin_amdgcn_mfma_f32_16x16x32_bf16(aF[i], bF[j], as[i][j], 0, 0, 0);
        }
    }
    __syncthreads();
    stage64x64(DT1 + b * 4096, 64, ls + 1 * 8192, t);
    stage64x64(DT2 + b * 4096, 64, ls + 2 * 8192, t);
    stage64x64(X2o + (size_t)n0 * 512 + b * 64, 512, ls + 3 * 8192, t);
    __syncthreads();
#pragma unroll
    for (int s = 0; s < 2; ++s) {
        const int kb = s * 64 + l4 * 16;
        bf16x8 a1[2], a2[2], b0[2], b3[2];
#pragma unroll
        for (int f = 0; f < 2; ++f) {
            a1[f] = fragld(ls + 1 * 8192, wr * 32 + f * 16 + l15, kb);
            a2[f] = fragld(ls + 2 * 8192, wr * 32 + f * 16 + l15, kb);
            b0[f] = fragld(ls + 0 * 8192, wc * 32 + f * 16 + l15, kb);
            b3[f] = fragld(ls + 3 * 8192, wc * 32 + f * 16 + l15, kb);
        }
#pragma unroll
        for (int i = 0; i < 2; ++i)
#pragma unroll
            for (int j = 0; j < 2; ++j) {
                f32x4 a = ad[i][j];
                a = __builtin_amdgcn_mfma_f32_16x16x32_bf16(a1[i], b0[j], a, 0, 0, 0);
                a = __builtin_amdgcn_mfma_f32_16x16x32_bf16(a1[i], b3[j], a, 0, 0, 0);
                a = __builtin_amdgcn_mfma_f32_16x16x32_bf16(a2[i], b0[j], a, 0, 0, 0);
                ad[i][j] = a;
            }
    }
#pragma unroll
    for (int i = 0; i < 2; ++i)
#pragma unroll
        for (int j = 0; j < 2; ++j) {
            const int ob = wr * 32 + i * 16 + l4 * 4;
            const int nn = wc * 32 + j * 16 + l15;
            float4 o4;
            o4.x = fmaxf(as[i][j][0], 0.f) + fmaxf(ad[i][j][0], 0.f);
            o4.y = fmaxf(as[i][j][1], 0.f) + fmaxf(ad[i][j][1], 0.f);
            o4.z = fmaxf(as[i][j][2], 0.f) + fmaxf(ad[i][j][2], 0.f);
            o4.w = fmaxf(as[i][j][3], 0.f) + fmaxf(ad[i][j][3], 0.f);
            *(float4*)&out[((size_t)b * 2048 + n0 + nn) * 64 + ob] = o4;
        }
}

extern "C" void kernel_launch(void* const* d_in, const int* in_sizes, int n_in,
                              void* d_out, int out_size, void* d_ws, size_t ws_size,
                              hipStream_t stream) {
    const float* X   = (const float*)d_in[0];
    const float* Ws  = (const float*)d_in[1];
    const float* Wa  = (const float*)d_in[2];
    const float* Ths = (const float*)d_in[3];
    const float* Thd = (const float*)d_in[4];

    char* p = (char*)d_ws;
    auto alloc = [&](size_t bytes) { char* r = p; p += (bytes + 255) & ~(size_t)255; return r; };
    ushort* XT1 = (ushort*)alloc(512ull * 2048 * 2);
    ushort* XT2 = (ushort*)alloc(512ull * 2048 * 2);
    ushort* X1o = (ushort*)alloc(2048ull * 512 * 2);
    ushort* X2o = (ushort*)alloc(2048ull * 512 * 2);
    ushort* Ws16 = (ushort*)alloc(2048ull * 2048 * 2);
    ushort* Wa1 = (ushort*)alloc(2048ull * 2048 * 2);
    ushort* Wa2 = (ushort*)alloc(2048ull * 2048 * 2);
    ushort* Y1T = (ushort*)alloc(512ull * 2048 * 2);
    ushort* Y2T = (ushort*)alloc(512ull * 2048 * 2);
    ushort* Y3T = (ushort*)alloc(512ull * 2048 * 2);
    ushort* Y1o = (ushort*)alloc(2048ull * 512 * 2);
    ushort* Y2o = (ushort*)alloc(2048ull * 512 * 2);
    ushort* Y3o = (ushort*)alloc(2048ull * 512 * 2);
    float*  Gpart = (float*)alloc(8ull * 8 * 4096 * 4);
    float*  G = (float*)alloc(8ull * 4096 * 4);
    ushort* DT1 = (ushort*)alloc(8ull * 4096 * 2);
    ushort* DT2 = (ushort*)alloc(8ull * 4096 * 2);
    ushort* ThsT = (ushort*)alloc(4ull * 4096 * 2);
    if ((size_t)(p - (char*)d_ws) > ws_size) return;   // visible failure if ws too small
    float* WaXT = (float*)d_out;                       // 4MB scratch, overwritten by ep_fused later

    prep_xt<<<dim3(32, 8), 256, 0, stream>>>(X, XT1, XT2, X1o, X2o);
    conv_ws<<<4096, 256, 0, stream>>>(Ws, Ws16);
    conv_wa<<<4096, 256, 0, stream>>>(Wa, Wa1, Wa2);
    conv_tht<<<64, 256, 0, stream>>>(Ths, ThsT);

    gemm_s<0><<<dim3(32, 8), 512, 0, stream>>>(Ws16, XT1, nullptr, Y1T, Y1o);
    gemm_s<1><<<dim3(32, 8), 512, 0, stream>>>(Ws16, Y1T, XT1, Y2T, Y2o);
    gemm_s<1><<<dim3(32, 8), 512, 0, stream>>>(Ws16, Y2T, Y1T, Y3T, Y3o);

    gemm3<<<dim3(32, 8), 512, 0, stream>>>(Wa1, Wa2, XT1, XT2, WaXT);
    gram<<<dim3(8, 8), 256, 0, stream>>>(WaXT, XT1, XT2, Gpart);
    reduce_g<<<128, 256, 0, stream>>>(Gpart, G);
    cheb_dt<<<8, 256, 0, stream>>>(G, Thd, DT1, DT2);

    ep_fused<<<dim3(32, 8), 256, 0, stream>>>(ThsT, DT1, DT2, X1o, X2o, Y1o, Y2o, Y3o, (float*)d_out);
}

// Round 4
// 88.707 us; speedup vs baseline: 6.0936x; 1.5814x over previous
//
#include <hip/hip_runtime.h>

typedef __attribute__((ext_vector_type(8))) short bf16x8;
typedef __attribute__((ext_vector_type(4))) float f32x4;

__device__ __forceinline__ ushort f32_to_bf16(float f) {
    union { float f; unsigned u; } v; v.f = f;
    unsigned b = v.u + 0x7FFF + ((v.u >> 16) & 1);
    return (ushort)(b >> 16);
}
__device__ __forceinline__ float bf16_to_f32(ushort h) {
    union { unsigned u; float f; } v; v.u = ((unsigned)h) << 16;
    return v.f;
}
__device__ __forceinline__ void split2(float x, ushort& a, ushort& b) {
    a = f32_to_bf16(x); float r1 = x - bf16_to_f32(a);
    b = f32_to_bf16(r1);
}

__device__ __forceinline__ void vmwait4() { asm volatile("s_waitcnt vmcnt(4)" ::: "memory"); }
__device__ __forceinline__ void vmwait0() { asm volatile("s_waitcnt vmcnt(0)" ::: "memory"); }
__device__ __forceinline__ void lgwait0() { asm volatile("s_waitcnt lgkmcnt(0)" ::: "memory"); }
__device__ __forceinline__ void blockbar() {
    __builtin_amdgcn_sched_barrier(0);
    __builtin_amdgcn_s_barrier();
    __builtin_amdgcn_sched_barrier(0);
}

// Stage a 64-row x 128-byte tile from global (row-major) into 8KB LDS with XOR
// swizzle applied via the GLOBAL source address (linear LDS dest, rule #21);
// read side (fragld) applies the same XOR. t256 in [0,256), 2 chunks/thread.
__device__ __forceinline__ void stage64x64(const ushort* gsrc, int row_stride_elems,
                                           char* lds, int t256) {
    const char* gb = (const char*)gsrc;
    const int rs = row_stride_elems * 2;
#pragma unroll
    for (int j = 0; j < 2; ++j) {
        int o = (j * 256 + t256) * 16;
        int row = o >> 7;
        int col = (o & 127) ^ ((row & 7) << 4);
        __builtin_amdgcn_global_load_lds(
            (const __attribute__((address_space(1))) unsigned int*)(gb + row * rs + col),
            (__attribute__((address_space(3))) unsigned int*)(lds + o), 16, 0, 0);
    }
}

__device__ __forceinline__ bf16x8 fragld(const char* lds, int row, int kbyte) {
    return *(const bf16x8*)(lds + (row << 7) + (kbyte ^ ((row & 7) << 4)));
}

// =================== prep_all: fused prep_xt / conv_ws / conv_wa / conv_tht ===================
__global__ __launch_bounds__(256) void prep_all(const float* __restrict__ X,
        ushort* __restrict__ XT1, ushort* __restrict__ XT2,
        ushort* __restrict__ X1o, ushort* __restrict__ X2o,
        const float* __restrict__ Ws, ushort* __restrict__ Ws16,
        const float* __restrict__ Wa, ushort* __restrict__ Wa1, ushort* __restrict__ Wa2,
        const float* __restrict__ Ths, ushort* __restrict__ ThsT) {
    __shared__ float tile[64][68];
    const int bx = blockIdx.x;
    const int t = threadIdx.x;
    if (bx < 256) {                       // ---- prep_xt ----
        const int b = bx >> 5, n0 = (bx & 31) * 64;
#pragma unroll
        for (int it = 0; it < 4; ++it) {
            int f = it * 256 + t, r = f >> 4, q = (f & 15) * 4;
            float4 v = *(const float4*)&X[((size_t)b * 2048 + n0 + r) * 64 + q];
            tile[r][q + 0] = v.x; tile[r][q + 1] = v.y; tile[r][q + 2] = v.z; tile[r][q + 3] = v.w;
        }
        __syncthreads();
#pragma unroll
        for (int it = 0; it < 4; ++it) {  // T-layout: row = b*64+c, cols n
            int f = it * 256 + t, c = f >> 4, q = (f & 15) * 4;
            ushort4 h1, h2;
            split2(tile[q + 0][c], h1.x, h2.x); split2(tile[q + 1][c], h1.y, h2.y);
            split2(tile[q + 2][c], h1.z, h2.z); split2(tile[q + 3][c], h1.w, h2.w);
            size_t a = (size_t)(b * 64 + c) * 2048 + n0 + q;
            *(ushort4*)&XT1[a] = h1; *(ushort4*)&XT2[a] = h2;
        }
#pragma unroll
        for (int it = 0; it < 4; ++it) {  // orig layout: row n, cols bc
            int f = it * 256 + t, n = f >> 4, q = (f & 15) * 4;
            ushort4 h1, h2;
            split2(tile[n][q + 0], h1.x, h2.x); split2(tile[n][q + 1], h1.y, h2.y);
            split2(tile[n][q + 2], h1.z, h2.z); split2(tile[n][q + 3], h1.w, h2.w);
            size_t a = (size_t)(n0 + n) * 512 + b * 64 + q;
            *(ushort4*)&X1o[a] = h1; *(ushort4*)&X2o[a] = h2;
        }
    } else if (bx < 2304) {               // ---- conv_ws: 8 elems/thread ----
        size_t idx = ((size_t)(bx - 256) * 256 + t) * 8;
#pragma unroll
        for (int h = 0; h < 2; ++h) {
            float4 v = *(const float4*)&Ws[idx + h * 4];
            ushort4 a;
            a.x = f32_to_bf16(v.x); a.y = f32_to_bf16(v.y);
            a.z = f32_to_bf16(v.z); a.w = f32_to_bf16(v.w);
            *(ushort4*)&Ws16[idx + h * 4] = a;
        }
    } else if (bx < 4352) {               // ---- conv_wa split2 ----
        size_t idx = ((size_t)(bx - 2304) * 256 + t) * 8;
#pragma unroll
        for (int h = 0; h < 2; ++h) {
            float4 v = *(const float4*)&Wa[idx + h * 4];
            ushort4 a, b;
            split2(v.x, a.x, b.x); split2(v.y, a.y, b.y);
            split2(v.z, a.z, b.z); split2(v.w, a.w, b.w);
            *(ushort4*)&Wa1[idx + h * 4] = a; *(ushort4*)&Wa2[idx + h * 4] = b;
        }
    } else {                              // ---- conv_tht (transpose Theta_s) ----
        int idx = (bx - 4352) * 256 + t;  // k*4096 + o*64 + i
        int k = idx >> 12, o = (idx >> 6) & 63, i = idx & 63;
        ThsT[idx] = f32_to_bf16(Ths[k * 4096 + i * 64 + o]);
    }
}

// =================== gemm_s body: 2-phase dbuf pipeline, in-block K-split ===================
template <int MODE>
__device__ __forceinline__ void gemm_s_body(int bx, const ushort* __restrict__ A,
        const ushort* __restrict__ BT, const ushort* __restrict__ CinT,
        ushort* __restrict__ YT, ushort* __restrict__ Yo, char* ls) {
    const int t = threadIdx.x;
    const int g = t >> 8, t256 = t & 255;
    const int m0 = (bx & 31) * 64, c0 = (bx >> 5) * 64;
    const int lane = t & 63;
    const int wg = (t >> 6) & 3, wr = wg >> 1, wc = wg & 1;
    const int l15 = lane & 15, l4 = lane >> 4;
    char* base = ls + g * 32768;          // per group: buf0 {A,B} | buf1 {A,B}
    const ushort* Ap = A + (size_t)m0 * 2048 + (size_t)g * 1024;
    const ushort* Bp = BT + (size_t)c0 * 2048 + (size_t)g * 1024;

    f32x4 z = {0.f, 0.f, 0.f, 0.f};
    f32x4 acc[2][2];
    acc[0][0] = z; acc[0][1] = z; acc[1][0] = z; acc[1][1] = z;

    stage64x64(Ap, 2048, base, t256);
    stage64x64(Bp, 2048, base + 8192, t256);
    for (int ts = 0; ts < 16; ++ts) {
        char* cur = base + (ts & 1) * 16384;
        if (ts < 15) {
            char* nxt = base + ((ts + 1) & 1) * 16384;
            stage64x64(Ap + (ts + 1) * 64, 2048, nxt, t256);
            stage64x64(Bp + (ts + 1) * 64, 2048, nxt + 8192, t256);
            vmwait4();                    // my 4 loads for cur are done
        } else {
            vmwait0();
        }
        blockbar();                       // everyone's cur loads done
#pragma unroll
        for (int s = 0; s < 2; ++s) {
            const int kb = s * 64 + l4 * 16;
            bf16x8 aF[2], bF[2];
#pragma unroll
            for (int f = 0; f < 2; ++f) {
                aF[f] = fragld(cur, wr * 32 + f * 16 + l15, kb);
                bF[f] = fragld(cur + 8192, wc * 32 + f * 16 + l15, kb);
            }
#pragma unroll
            for (int i = 0; i < 2; ++i)
#pragma unroll
                for (int j = 0; j < 2; ++j)
                    acc[i][j] = __builtin_amdgcn_mfma_f32_16x16x32_bf16(aF[i], bF[j], acc[i][j], 0, 0, 0);
        }
        lgwait0();                        // my ds_reads of cur done
        blockbar();                       // everyone done reading cur -> reusable
    }

    // cross-group reduce + epilogue (post-pipeline; plain syncthreads fine)
    float* red = (float*)ls;              // 64*65*4 = 16640 B
    ushort* tileo = (ushort*)(ls + 17408);
    if (g == 0) {
#pragma unroll
        for (int i = 0; i < 2; ++i)
#pragma unroll
            for (int j = 0; j < 2; ++j) {
                const int lrb = wr * 32 + i * 16 + l4 * 4;
                const int lc = wc * 32 + j * 16 + l15;
#pragma unroll
                for (int r = 0; r < 4; ++r) red[(lrb + r) * 65 + lc] = acc[i][j][r];
            }
    }
    __syncthreads();
    if (g == 1) {
#pragma unroll
        for (int i = 0; i < 2; ++i)
#pragma unroll
            for (int j = 0; j < 2; ++j) {
                const int lrb = wr * 32 + i * 16 + l4 * 4;
                const int lc = wc * 32 + j * 16 + l15;
                float vv[4];
#pragma unroll
                for (int r = 0; r < 4; ++r) vv[r] = red[(lrb + r) * 65 + lc] + acc[i][j][r];
                if (MODE == 1) {
                    ushort4 ci = *(const ushort4*)&CinT[(size_t)(c0 + lc) * 2048 + m0 + lrb];
                    vv[0] = 2.f * vv[0] - bf16_to_f32(ci.x);
                    vv[1] = 2.f * vv[1] - bf16_to_f32(ci.y);
                    vv[2] = 2.f * vv[2] - bf16_to_f32(ci.z);
                    vv[3] = 2.f * vv[3] - bf16_to_f32(ci.w);
                }
                ushort4 p;
                p.x = f32_to_bf16(vv[0]); p.y = f32_to_bf16(vv[1]);
                p.z = f32_to_bf16(vv[2]); p.w = f32_to_bf16(vv[3]);
                *(ushort4*)&YT[(size_t)(c0 + lc) * 2048 + m0 + lrb] = p;
                tileo[(lrb + 0) * 64 + lc] = p.x;
                tileo[(lrb + 1) * 64 + lc] = p.y;
                tileo[(lrb + 2) * 64 + lc] = p.z;
                tileo[(lrb + 3) * 64 + lc] = p.w;
            }
    }
    __syncthreads();
    {
        int row = t >> 3, ch = t & 7;
        *(uint4*)&Yo[(size_t)(m0 + row) * 512 + c0 + ch * 8] = *(uint4*)&tileo[row * 64 + ch * 8];
    }
}

// =================== gemm3 body: WaX split-2 (3 products), in-block K-split ===================
__device__ __forceinline__ void gemm3_body(int bx, const ushort* __restrict__ A1,
        const ushort* __restrict__ A2, const ushort* __restrict__ B1,
        const ushort* __restrict__ B2, float* __restrict__ WaXT, char* ls) {
    const int t = threadIdx.x;
    const int g = t >> 8, t256 = t & 255;
    const int m0 = (bx & 31) * 64, c0 = (bx >> 5) * 64;
    const int lane = t & 63;
    const int wg = (t >> 6) & 3, wr = wg >> 1, wc = wg & 1;
    const int l15 = lane & 15, l4 = lane >> 4;
    char* base = ls + g * 32768;
    const size_t kbase = (size_t)g * 1024;

    f32x4 z = {0.f, 0.f, 0.f, 0.f};
    f32x4 acc[2][2];
    acc[0][0] = z; acc[0][1] = z; acc[1][0] = z; acc[1][1] = z;

    for (int k0 = 0; k0 < 1024; k0 += 64) {
        stage64x64(A1 + (size_t)m0 * 2048 + kbase + k0, 2048, base + 0 * 8192, t256);
        stage64x64(A2 + (size_t)m0 * 2048 + kbase + k0, 2048, base + 1 * 8192, t256);
        stage64x64(B1 + (size_t)c0 * 2048 + kbase + k0, 2048, base + 2 * 8192, t256);
        stage64x64(B2 + (size_t)c0 * 2048 + kbase + k0, 2048, base + 3 * 8192, t256);
        __syncthreads();
#pragma unroll
        for (int s = 0; s < 2; ++s) {
            const int kb = s * 64 + l4 * 16;
            bf16x8 a1F[2], a2F[2], b1F[2], b2F[2];
#pragma unroll
            for (int f = 0; f < 2; ++f) {
                const int ar = wr * 32 + f * 16 + l15;
                const int br = wc * 32 + f * 16 + l15;
                a1F[f] = fragld(base + 0 * 8192, ar, kb);
                a2F[f] = fragld(base + 1 * 8192, ar, kb);
                b1F[f] = fragld(base + 2 * 8192, br, kb);
                b2F[f] = fragld(base + 3 * 8192, br, kb);
            }
#pragma unroll
            for (int i = 0; i < 2; ++i)
#pragma unroll
                for (int j = 0; j < 2; ++j) {
                    f32x4 a = acc[i][j];
                    a = __builtin_amdgcn_mfma_f32_16x16x32_bf16(a1F[i], b1F[j], a, 0, 0, 0);
                    a = __builtin_amdgcn_mfma_f32_16x16x32_bf16(a1F[i], b2F[j], a, 0, 0, 0);
                    a = __builtin_amdgcn_mfma_f32_16x16x32_bf16(a2F[i], b1F[j], a, 0, 0, 0);
                    acc[i][j] = a;
                }
        }
        __syncthreads();
    }

    float* red = (float*)ls;
    if (g == 0) {
#pragma unroll
        for (int i = 0; i < 2; ++i)
#pragma unroll
            for (int j = 0; j < 2; ++j) {
                const int lrb = wr * 32 + i * 16 + l4 * 4;
                const int lc = wc * 32 + j * 16 + l15;
#pragma unroll
                for (int r = 0; r < 4; ++r) red[(lrb + r) * 65 + lc] = acc[i][j][r];
            }
    }
    __syncthreads();
    if (g == 1) {
#pragma unroll
        for (int i = 0; i < 2; ++i)
#pragma unroll
            for (int j = 0; j < 2; ++j) {
                const int lrb = wr * 32 + i * 16 + l4 * 4;
                const int lc = wc * 32 + j * 16 + l15;
                f32x4 v;
#pragma unroll
                for (int r = 0; r < 4; ++r) v[r] = red[(lrb + r) * 65 + lc] + acc[i][j][r];
                *(f32x4*)&WaXT[(size_t)(c0 + lc) * 2048 + m0 + lrb] = v;
            }
    }
}

// =================== gram body: 256 blocks (8 b x 32 chunks of 64 n), 512 thr ===================
__device__ __forceinline__ void gram_body(int bx, const float* __restrict__ WaXT,
        const ushort* __restrict__ XT1, const ushort* __restrict__ XT2,
        float* __restrict__ Gpart, char* lsraw) {
    const int b = bx & 7, chunk = bx >> 3;
    float (*Lw)[68] = (float(*)[68])lsraw;
    float (*Rx)[68] = (float(*)[68])(lsraw + 64 * 68 * 4);
    const int t = threadIdx.x;
    const int n0 = chunk * 64;
    {   // all 512 threads load 64x64 of Lw and Rx (8 f32 each)
        const int r = t >> 3, q = (t & 7) * 8;
        size_t a = (size_t)(b * 64 + r) * 2048 + n0 + q;
        *(float4*)&Lw[r][q]     = *(const float4*)&WaXT[a];
        *(float4*)&Lw[r][q + 4] = *(const float4*)&WaXT[a + 4];
#pragma unroll
        for (int h = 0; h < 2; ++h) {
            ushort4 h1 = *(const ushort4*)&XT1[a + h * 4];
            ushort4 h2 = *(const ushort4*)&XT2[a + h * 4];
            Rx[r][q + h * 4 + 0] = bf16_to_f32(h1.x) + bf16_to_f32(h2.x);
            Rx[r][q + h * 4 + 1] = bf16_to_f32(h1.y) + bf16_to_f32(h2.y);
            Rx[r][q + h * 4 + 2] = bf16_to_f32(h1.z) + bf16_to_f32(h2.z);
            Rx[r][q + h * 4 + 3] = bf16_to_f32(h1.w) + bf16_to_f32(h2.w);
        }
    }
    __syncthreads();
    if (t < 256) {
        const int tx = t & 15, ty = t >> 4;
        float acc[4][4] = {{0.f,0.f,0.f,0.f},{0.f,0.f,0.f,0.f},{0.f,0.f,0.f,0.f},{0.f,0.f,0.f,0.f}};
        for (int n = 0; n < 64; ++n) {
            float a[4], bb[4];
#pragma unroll
            for (int i = 0; i < 4; ++i) { a[i] = Lw[ty * 4 + i][n]; bb[i] = Rx[tx * 4 + i][n]; }
#pragma unroll
            for (int i = 0; i < 4; ++i)
#pragma unroll
                for (int j = 0; j < 4; ++j) acc[i][j] = fmaf(a[i], bb[j], acc[i][j]);
        }
        float* gp = Gpart + (size_t)(chunk * 8 + b) * 4096;
#pragma unroll
        for (int i = 0; i < 4; ++i)
            *(float4*)&gp[(ty * 4 + i) * 64 + tx * 4] =
                make_float4(acc[i][0], acc[i][1], acc[i][2], acc[i][3]);
    }
}

// =================== cheb body: per-batch 64x64 Chebyshev; 512 thr, t<256 compute ===================
__device__ __forceinline__ void cheb_body(int b, const float* __restrict__ Gpart,
        const float* __restrict__ Thd, ushort* __restrict__ DT1, ushort* __restrict__ DT2,
        char* lsraw) {
    float (*Gs)[68]  = (float(*)[68])lsraw;
    float (*C2s)[68] = (float(*)[68])(lsraw + 17408);
    float (*C3s)[68] = (float(*)[68])(lsraw + 34816);
    const int t = threadIdx.x;
    for (int i = t; i < 4096; i += 512) {      // fold 32-chunk reduce in
        float s = 0.f;
#pragma unroll
        for (int c = 0; c < 32; ++c) s += Gpart[((size_t)c * 8 + b) * 4096 + i];
        Gs[i >> 6][i & 63] = s;
    }
    __syncthreads();
    const int tx = t & 15, ty = (t >> 4) & 15;
    const int r0 = ty * 4, c0 = tx * 4;
    const bool act = t < 256;

    if (act) {   // C2 = 2*G@G - I
        float p[4][4] = {{0,0,0,0},{0,0,0,0},{0,0,0,0},{0,0,0,0}};
        for (int k = 0; k < 64; ++k) {
            float ar[4] = {Gs[r0][k], Gs[r0+1][k], Gs[r0+2][k], Gs[r0+3][k]};
            float4 bv = *(const float4*)&Gs[k][c0];
            float br[4] = {bv.x, bv.y, bv.z, bv.w};
#pragma unroll
            for (int i = 0; i < 4; ++i)
#pragma unroll
                for (int j = 0; j < 4; ++j) p[i][j] = fmaf(ar[i], br[j], p[i][j]);
        }
#pragma unroll
        for (int i = 0; i < 4; ++i)
#pragma unroll
            for (int j = 0; j < 4; ++j)
                C2s[r0+i][c0+j] = 2.f * p[i][j] - ((r0+i) == (c0+j) ? 1.f : 0.f);
    }
    __syncthreads();
    if (act) {   // C3 = 2*G@C2 - G
        float q[4][4] = {{0,0,0,0},{0,0,0,0},{0,0,0,0},{0,0,0,0}};
        for (int k = 0; k < 64; ++k) {
            float ar[4] = {Gs[r0][k], Gs[r0+1][k], Gs[r0+2][k], Gs[r0+3][k]};
            float4 bv = *(const float4*)&C2s[k][c0];
            float br[4] = {bv.x, bv.y, bv.z, bv.w};
#pragma unroll
            for (int i = 0; i < 4; ++i)
#pragma unroll
                for (int j = 0; j < 4; ++j) q[i][j] = fmaf(ar[i], br[j], q[i][j]);
        }
#pragma unroll
        for (int i = 0; i < 4; ++i)
#pragma unroll
            for (int j = 0; j < 4; ++j)
                C3s[r0+i][c0+j] = 2.f * q[i][j] - Gs[r0+i][c0+j];
    }
    __syncthreads();
    float d[4][4];
    if (act) {   // D = Thd0 + G@Thd1 + C2@Thd2 + C3@Thd3
#pragma unroll
        for (int i = 0; i < 4; ++i) {
            float4 t0 = *(const float4*)&Thd[(r0+i) * 64 + c0];
            d[i][0] = t0.x; d[i][1] = t0.y; d[i][2] = t0.z; d[i][3] = t0.w;
        }
        for (int k = 0; k < 64; ++k) {
            float4 t1 = *(const float4*)&Thd[4096 + k * 64 + c0];
            float4 t2 = *(const float4*)&Thd[8192 + k * 64 + c0];
            float4 t3 = *(const float4*)&Thd[12288 + k * 64 + c0];
            float a1[4] = {Gs[r0][k], Gs[r0+1][k], Gs[r0+2][k], Gs[r0+3][k]};
            float a2[4] = {C2s[r0][k], C2s[r0+1][k], C2s[r0+2][k], C2s[r0+3][k]};
            float a3[4] = {C3s[r0][k], C3s[r0+1][k], C3s[r0+2][k], C3s[r0+3][k]};
            float b1[4] = {t1.x, t1.y, t1.z, t1.w};
            float b2[4] = {t2.x, t2.y, t2.z, t2.w};
            float b3[4] = {t3.x, t3.y, t3.z, t3.w};
#pragma unroll
            for (int i = 0; i < 4; ++i)
#pragma unroll
                for (int j = 0; j < 4; ++j) {
                    d[i][j] = fmaf(a1[i], b1[j], d[i][j]);
                    d[i][j] = fmaf(a2[i], b2[j], d[i][j]);
                    d[i][j] = fmaf(a3[i], b3[j], d[i][j]);
                }
        }
    }
    __syncthreads();
    if (act) {
#pragma unroll
        for (int i = 0; i < 4; ++i)
#pragma unroll
            for (int j = 0; j < 4; ++j) Gs[r0 + i][c0 + j] = d[i][j];
    }
    __syncthreads();
    for (int it = 0; it < 8; ++it) {
        int idx = it * 512 + t;              // o*64 + i (transposed emit)
        int o = idx >> 6, ii = idx & 63;
        ushort h1, h2;
        split2(Gs[ii][o], h1, h2);
        DT1[b * 4096 + idx] = h1;
        DT2[b * 4096 + idx] = h2;
    }
}

// =================== mega kernels: block-role fusion for co-residency ===================
__global__ __launch_bounds__(512, 4) void mega1(const ushort* __restrict__ Wa1,
        const ushort* __restrict__ Wa2, const ushort* __restrict__ XT1,
        const ushort* __restrict__ XT2, float* __restrict__ WaXT,
        const ushort* __restrict__ Ws16, ushort* __restrict__ Y1T, ushort* __restrict__ Y1o) {
    __shared__ __align__(16) char ls[65536];
    const int bx = blockIdx.x;
    if (bx < 256) gemm3_body(bx, Wa1, Wa2, XT1, XT2, WaXT, ls);
    else          gemm_s_body<0>(bx - 256, Ws16, XT1, nullptr, Y1T, Y1o, ls);
}

__global__ __launch_bounds__(512, 4) void mega2(const ushort* __restrict__ Ws16,
        const ushort* __restrict__ Y1T, const ushort* __restrict__ XT1,
        ushort* __restrict__ Y2T, ushort* __restrict__ Y2o,
        const float* __restrict__ WaXT, const ushort* __restrict__ XT2,
        float* __restrict__ Gpart) {
    __shared__ __align__(16) char ls[65536];
    const int bx = blockIdx.x;
    if (bx < 256) gemm_s_body<1>(bx, Ws16, Y1T, XT1, Y2T, Y2o, ls);
    else          gram_body(bx - 256, WaXT, XT1, XT2, Gpart, ls);
}

__global__ __launch_bounds__(512, 4) void mega3(const ushort* __restrict__ Ws16,
        const ushort* __restrict__ Y2T, const ushort* __restrict__ Y1T,
        ushort* __restrict__ Y3T, ushort* __restrict__ Y3o,
        const float* __restrict__ Gpart, const float* __restrict__ Thd,
        ushort* __restrict__ DT1, ushort* __restrict__ DT2) {
    __shared__ __align__(16) char ls[65536];
    const int bx = blockIdx.x;
    if (bx < 256) gemm_s_body<1>(bx, Ws16, Y2T, Y1T, Y3T, Y3o, ls);
    else          cheb_body(bx - 256, Gpart, Thd, DT1, DT2, ls);
}

// =================== fused epilogue (unchanged from R3) ===================
__global__ __launch_bounds__(256) void ep_fused(const ushort* __restrict__ ThsT,
                                                const ushort* __restrict__ DT1, const ushort* __restrict__ DT2,
                                                const ushort* __restrict__ X1o, const ushort* __restrict__ X2o,
                                                const ushort* __restrict__ Y1o, const ushort* __restrict__ Y2o,
                                                const ushort* __restrict__ Y3o,
                                                float* __restrict__ out) {
    __shared__ __align__(16) char ls[65536];
    const int b = blockIdx.y, n0 = blockIdx.x * 64;
    const int t = threadIdx.x, lane = t & 63, w = t >> 6, wr = w >> 1, wc = w & 1;
    const int l15 = lane & 15, l4 = lane >> 4;
    stage64x64(X1o + (size_t)n0 * 512 + b * 64, 512, ls + 0 * 8192, t);
    stage64x64(Y1o + (size_t)n0 * 512 + b * 64, 512, ls + 1 * 8192, t);
    stage64x64(Y2o + (size_t)n0 * 512 + b * 64, 512, ls + 2 * 8192, t);
    stage64x64(Y3o + (size_t)n0 * 512 + b * 64, 512, ls + 3 * 8192, t);
    stage64x64(ThsT + 0 * 4096, 64, ls + 4 * 8192, t);
    stage64x64(ThsT + 1 * 4096, 64, ls + 5 * 8192, t);
    stage64x64(ThsT + 2 * 4096, 64, ls + 6 * 8192, t);
    stage64x64(ThsT + 3 * 4096, 64, ls + 7 * 8192, t);
    __syncthreads();
    f32x4 z = {0.f, 0.f, 0.f, 0.f};
    f32x4 as[2][2], ad[2][2];
    as[0][0] = z; as[0][1] = z; as[1][0] = z; as[1][1] = z;
    ad[0][0] = z; ad[0][1] = z; ad[1][0] = z; ad[1][1] = z;
#pragma unroll
    for (int s = 0; s < 2; ++s) {
        const int kb = s * 64 + l4 * 16;
#pragma unroll
        for (int p = 0; p < 4; ++p) {
            bf16x8 aF[2], bF[2];
#pragma unroll
            for (int f = 0; f < 2; ++f) {
                aF[f] = fragld(ls + (4 + p) * 8192, wr * 32 + f * 16 + l15, kb);
                bF[f] = fragld(ls + p * 8192, wc * 32 + f * 16 + l15, kb);
            }
#pragma unroll
            for (int i = 0; i < 2; ++i)
#pragma unroll
                for (int j = 0; j < 2; ++j)
                    as[i][j] = __builtin_amdgcn_mfma_f32_16x16x32_bf16(aF[i], bF[j], as[i][j], 0, 0, 0);
        }
    }
    __syncthreads();
    stage64x64(DT1 + b * 4096, 64, ls + 1 * 8192, t);
    stage64x64(DT2 + b * 4096, 64, ls + 2 * 8192, t);
    stage64x64(X2o + (size_t)n0 * 512 + b * 64, 512, ls + 3 * 8192, t);
    __syncthreads();
#pragma unroll
    for (int s = 0; s < 2; ++s) {
        const int kb = s * 64 + l4 * 16;
        bf16x8 a1[2], a2[2], b0[2], b3[2];
#pragma unroll
        for (int f = 0; f < 2; ++f) {
            a1[f] = fragld(ls + 1 * 8192, wr * 32 + f * 16 + l15, kb);
            a2[f] = fragld(ls + 2 * 8192, wr * 32 + f * 16 + l15, kb);
            b0[f] = fragld(ls + 0 * 8192, wc * 32 + f * 16 + l15, kb);
            b3[f] = fragld(ls + 3 * 8192, wc * 32 + f * 16 + l15, kb);
        }
#pragma unroll
        for (int i = 0; i < 2; ++i)
#pragma unroll
            for (int j = 0; j < 2; ++j) {
                f32x4 a = ad[i][j];
                a = __builtin_amdgcn_mfma_f32_16x16x32_bf16(a1[i], b0[j], a, 0, 0, 0);
                a = __builtin_amdgcn_mfma_f32_16x16x32_bf16(a1[i], b3[j], a, 0, 0, 0);
                a = __builtin_amdgcn_mfma_f32_16x16x32_bf16(a2[i], b0[j], a, 0, 0, 0);
                ad[i][j] = a;
            }
    }
#pragma unroll
    for (int i = 0; i < 2; ++i)
#pragma unroll
        for (int j = 0; j < 2; ++j) {
            const int ob = wr * 32 + i * 16 + l4 * 4;
            const int nn = wc * 32 + j * 16 + l15;
            float4 o4;
            o4.x = fmaxf(as[i][j][0], 0.f) + fmaxf(ad[i][j][0], 0.f);
            o4.y = fmaxf(as[i][j][1], 0.f) + fmaxf(ad[i][j][1], 0.f);
            o4.z = fmaxf(as[i][j][2], 0.f) + fmaxf(ad[i][j][2], 0.f);
            o4.w = fmaxf(as[i][j][3], 0.f) + fmaxf(ad[i][j][3], 0.f);
            *(float4*)&out[((size_t)b * 2048 + n0 + nn) * 64 + ob] = o4;
        }
}

extern "C" void kernel_launch(void* const* d_in, const int* in_sizes, int n_in,
                              void* d_out, int out_size, void* d_ws, size_t ws_size,
                              hipStream_t stream) {
    (void)in_sizes; (void)n_in; (void)out_size;
    const float* X   = (const float*)d_in[0];
    const float* Ws  = (const float*)d_in[1];
    const float* Wa  = (const float*)d_in[2];
    const float* Ths = (const float*)d_in[3];
    const float* Thd = (const float*)d_in[4];

    char* p = (char*)d_ws;
    auto alloc = [&](size_t bytes) { char* r = p; p += (bytes + 255) & ~(size_t)255; return r; };
    ushort* XT1 = (ushort*)alloc(512ull * 2048 * 2);
    ushort* XT2 = (ushort*)alloc(512ull * 2048 * 2);
    ushort* X1o = (ushort*)alloc(2048ull * 512 * 2);
    ushort* X2o = (ushort*)alloc(2048ull * 512 * 2);
    ushort* Ws16 = (ushort*)alloc(2048ull * 2048 * 2);
    ushort* Wa1 = (ushort*)alloc(2048ull * 2048 * 2);
    ushort* Wa2 = (ushort*)alloc(2048ull * 2048 * 2);
    ushort* Y1T = (ushort*)alloc(512ull * 2048 * 2);
    ushort* Y2T = (ushort*)alloc(512ull * 2048 * 2);
    ushort* Y3T = (ushort*)alloc(512ull * 2048 * 2);
    ushort* Y1o = (ushort*)alloc(2048ull * 512 * 2);
    ushort* Y2o = (ushort*)alloc(2048ull * 512 * 2);
    ushort* Y3o = (ushort*)alloc(2048ull * 512 * 2);
    float*  Gpart = (float*)alloc(32ull * 8 * 4096 * 4);
    ushort* DT1 = (ushort*)alloc(8ull * 4096 * 2);
    ushort* DT2 = (ushort*)alloc(8ull * 4096 * 2);
    ushort* ThsT = (ushort*)alloc(4ull * 4096 * 2);
    if ((size_t)(p - (char*)d_ws) > ws_size) return;   // visible failure if ws too small
    float* WaXT = (float*)d_out;                       // 4MB scratch, overwritten by ep_fused later

    prep_all<<<4416, 256, 0, stream>>>(X, XT1, XT2, X1o, X2o, Ws, Ws16, Wa, Wa1, Wa2, Ths, ThsT);
    mega1<<<512, 512, 0, stream>>>(Wa1, Wa2, XT1, XT2, WaXT, Ws16, Y1T, Y1o);
    mega2<<<512, 512, 0, stream>>>(Ws16, Y1T, XT1, Y2T, Y2o, WaXT, XT2, Gpart);
    mega3<<<264, 512, 0, stream>>>(Ws16, Y2T, Y1T, Y3T, Y3o, Gpart, Thd, DT1, DT2);
    ep_fused<<<dim3(32, 8), 256, 0, stream>>>(ThsT, DT1, DT2, X1o, X2o, Y1o, Y2o, Y3o, (float*)d_out);
}